// Round 6
// baseline (1161.172 us; speedup 1.0000x reference)
//
#include <hip/hip_runtime.h>
#include <hip/hip_bf16.h>

#define NNODES 100000
#define NEDGES 3200000
#define NPADE  3600000  // NEDGES + 4*NNODES worst-case row padding
#define NPER   400
#define NGRAPH 250
#define KTOP   100
#define DIM    32
#define INDIM  128
#define TOTALC 97
#define BSHIFT 7
#define BNODES 128
#define NBUCK  782   // ceil(100000/128)
#define NCHUNK 1024
#define CHSZ   3125  // NEDGES / NCHUNK

__device__ __forceinline__ float bf(unsigned short u) {
    return __uint_as_float(((unsigned)u) << 16);
}
__device__ __forceinline__ unsigned short f2bf(float f) {
    unsigned u = __float_as_uint(f);
    unsigned r = ((u >> 16) & 1u) + 0x7FFFu;   // round-to-nearest-even
    return (unsigned short)((u + r) >> 16);
}

// converted-weights fp32 layout in ws (element offsets, padded to 8)
#define OW_W1   0
#define OW_B1   4096
#define OW_W2   4128
#define OW_B2   5152
#define OW_W3   5184
#define OW_B3   6208
#define OW_W4   6240
#define OW_B4   6272
#define OW_CW1  6280
#define OW_CB1  18696
#define OW_CW2  18824
#define OW_CB2  59784
#define OW_FW1  59848
#define OW_FB1  436680
#define OW_FW3  436808
#define OW_FB3  437064
#define OW_TOT  437072

// ---------------- dtype detect + weight convert ----------------

__global__ void k_detect(const unsigned int* __restrict__ xw, int* __restrict__ flag) {
    __shared__ int cnt[256];
    int t = threadIdx.x, c = 0;
    for (int i = t; i < 4096; i += 256) {
        unsigned e = (xw[i] >> 23) & 0xFFu;
        if (e >= 100u && e <= 150u) c++;
    }
    cnt[t] = c;
    __syncthreads();
    for (int off = 128; off > 0; off >>= 1) {
        if (t < off) cnt[t] += cnt[t + off];
        __syncthreads();
    }
    if (t == 0) flag[0] = (cnt[0] < 2048) ? 1 : 0;   // 1 = inputs are bf16
}

struct Srcs { const void* p[16]; };

__global__ void k_convert(Srcs sr, float* __restrict__ dst, const int* __restrict__ flag) {
    const int st[16] = {OW_W1, OW_B1, OW_W2, OW_B2, OW_W3, OW_B3, OW_W4, OW_B4,
                        OW_CW1, OW_CB1, OW_CW2, OW_CB2, OW_FW1, OW_FB1, OW_FW3, OW_FB3};
    const int nn[16] = {4096, 32, 1024, 32, 1024, 32, 32, 1,
                        12416, 128, 40960, 64, 376832, 128, 256, 2};
    int idx = blockIdx.x * 256 + threadIdx.x;
    if (idx >= OW_TOT) return;
    int isb = flag[0];
    #pragma unroll
    for (int s = 0; s < 16; s++) {
        if (idx >= st[s] && idx < st[s] + nn[s]) {
            int l = idx - st[s];
            dst[idx] = isb ? bf(((const unsigned short*)sr.p[s])[l])
                           : ((const float*)sr.p[s])[l];
        }
    }
}

// fw1 [128][2944] -> fw1t [2944][128] (one-time, L2-resident)
__global__ void k_w1t(const float* __restrict__ fw1f, float* __restrict__ fw1t) {
    int i = blockIdx.x * 256 + threadIdx.x;
    if (i < 376832) {
        int j = i / 2944, d = i % 2944;
        fw1t[d * 128 + j] = fw1f[i];
    }
}

// ---------------- graph prep: contention-free counting sort ----------------

__global__ __launch_bounds__(256) void k_hist(const int* __restrict__ ei, int* __restrict__ ghist) {
    __shared__ int h[NBUCK];
    int c = blockIdx.x, t = threadIdx.x;
    for (int i = t; i < NBUCK; i += 256) h[i] = 0;
    __syncthreads();
    int base = c * CHSZ;
    for (int e = base + t; e < base + CHSZ; e += 256)
        atomicAdd(&h[ei[NEDGES + e] >> BSHIFT], 1);
    __syncthreads();
    for (int i = t; i < NBUCK; i += 256) ghist[i * NCHUNK + c] = h[i];
}

__global__ __launch_bounds__(1024) void k_scanChunk(int* __restrict__ ghist, int* __restrict__ bcnt) {
    __shared__ int s[NCHUNK];
    int b = blockIdx.x, t = threadIdx.x;
    int v = ghist[b * NCHUNK + t];
    s[t] = v;
    __syncthreads();
    for (int o = 1; o < NCHUNK; o <<= 1) {
        int u = (t >= o) ? s[t - o] : 0;
        __syncthreads();
        s[t] += u;
        __syncthreads();
    }
    ghist[b * NCHUNK + t] = s[t] - v;   // exclusive within bucket
    if (t == NCHUNK - 1) bcnt[b] = s[t];
}

__global__ void k_scanB(const int* __restrict__ bcnt, int* __restrict__ boff) {
    __shared__ int s[1024];
    int t = threadIdx.x;
    int v = (t < NBUCK) ? bcnt[t] : 0;
    s[t] = v;
    __syncthreads();
    for (int o = 1; o < 1024; o <<= 1) {
        int u = (t >= o) ? s[t - o] : 0;
        __syncthreads();
        s[t] += u;
        __syncthreads();
    }
    if (t < NBUCK) boff[t] = s[t] - v;   // exclusive
}

__global__ __launch_bounds__(256) void k_binwrite(const int* __restrict__ ei, const int* __restrict__ boff,
                           const int* __restrict__ ghist, unsigned* __restrict__ staged) {
    __shared__ int cur[NBUCK];
    int c = blockIdx.x, t = threadIdx.x;
    for (int i = t; i < NBUCK; i += 256) cur[i] = boff[i] + ghist[i * NCHUNK + c];
    __syncthreads();
    int base = c * CHSZ;
    for (int e = base + t; e < base + CHSZ; e += 256) {
        int s = ei[e], d = ei[NEDGES + e];
        int b = d >> BSHIFT;
        int pos = atomicAdd(&cur[b], 1);
        staged[pos] = ((unsigned)(d & (BNODES - 1)) << 17) | (unsigned)s;
    }
}

__global__ __launch_bounds__(256) void k_nodecnt(const unsigned* __restrict__ staged,
                          const int* __restrict__ boff, int* __restrict__ degi) {
    __shared__ int cnt[BNODES];
    int b = blockIdx.x, t = threadIdx.x;
    if (t < BNODES) cnt[t] = 0;
    __syncthreads();
    int s0 = boff[b];
    int s1 = (b + 1 < NBUCK) ? boff[b + 1] : NEDGES;
    for (int i = s0 + t; i < s1; i += 256)
        atomicAdd(&cnt[staged[i] >> 17], 1);
    __syncthreads();
    int n0 = b << BSHIFT;
    int nn = min(BNODES, NNODES - n0);
    if (t < nn) degi[n0 + t] = cnt[t];
}

__global__ void k_nodeprep(const int* __restrict__ degi, float* __restrict__ dis,
                           float* __restrict__ dinv) {
    int i = blockIdx.x * 256 + threadIdx.x;
    if (i < NNODES) {
        float d = (float)(degi[i] + 1);
        dis[i]  = rsqrtf(d);
        dinv[i] = 1.0f / d;
    }
}

// scans below use PADDED degree (rounded up to 4) so CSR rows are 16B-aligned
__global__ void k_bsum(const int* __restrict__ degi, int* __restrict__ bsums) {
    __shared__ int s[256];
    int t = threadIdx.x;
    int i = blockIdx.x * 256 + t;
    s[t] = (i < NNODES) ? ((degi[i] + 3) & ~3) : 0;
    __syncthreads();
    for (int off = 128; off > 0; off >>= 1) {
        if (t < off) s[t] += s[t + off];
        __syncthreads();
    }
    if (t == 0) bsums[blockIdx.x] = s[0];
}

__global__ void k_scanb(int* __restrict__ bsums, int nb) {
    __shared__ int s[512];
    int t = threadIdx.x;
    int v = (t < nb) ? bsums[t] : 0;
    s[t] = v;
    __syncthreads();
    for (int off = 1; off < 512; off <<= 1) {
        int u = (t >= off) ? s[t - off] : 0;
        __syncthreads();
        s[t] += u;
        __syncthreads();
    }
    if (t < nb) bsums[t] = s[t] - v;   // exclusive
}

__global__ void k_scanf(const int* __restrict__ degi, const int* __restrict__ bsums,
                        int* __restrict__ row_off) {
    __shared__ int s[256];
    int t = threadIdx.x;
    int i = blockIdx.x * 256 + t;
    int v = (i < NNODES) ? ((degi[i] + 3) & ~3) : 0;
    s[t] = v;
    __syncthreads();
    for (int off = 1; off < 256; off <<= 1) {
        int u = (t >= off) ? s[t - off] : 0;
        __syncthreads();
        s[t] += u;
        __syncthreads();
    }
    if (i < NNODES) row_off[i] = bsums[blockIdx.x] + s[t] - v;  // exclusive
}

__global__ __launch_bounds__(256) void k_csrfix(const unsigned* __restrict__ staged,
                         const int* __restrict__ boff, const int* __restrict__ row_off,
                         const float* __restrict__ dis,
                         int* __restrict__ csr_src, float* __restrict__ csr_cf) {
    __shared__ int cnt[BNODES];
    __shared__ int rofs[BNODES];
    __shared__ float disl[BNODES];
    int b = blockIdx.x, t = threadIdx.x;
    int n0 = b << BSHIFT;
    int nn = min(BNODES, NNODES - n0);
    if (t < BNODES) {
        cnt[t]  = 0;
        rofs[t] = (t < nn) ? row_off[n0 + t] : 0;
        disl[t] = (t < nn) ? dis[n0 + t] : 0.f;
    }
    __syncthreads();
    int s0 = boff[b];
    int s1 = (b + 1 < NBUCK) ? boff[b + 1] : NEDGES;
    for (int i = s0 + t; i < s1; i += 256) {
        unsigned rec = staged[i];
        int dl = rec >> 17, s = rec & 0x1FFFF;
        int r = atomicAdd(&cnt[dl], 1);
        int slot = rofs[dl] + r;
        csr_src[slot] = s;
        csr_cf[slot]  = dis[s] * disl[dl];
    }
    __syncthreads();
    if (t < nn) {   // inert pad entries: src=0 (harmless read), cf=0
        int d = cnt[t], dp = (d + 3) & ~3;
        for (int s2 = d; s2 < dp; s2++) {
            csr_src[rofs[t] + s2] = 0;
            csr_cf[rofs[t] + s2]  = 0.f;
        }
    }
}

// ---------------- GCN dense parts ----------------

__global__ void k_mm1(const void* __restrict__ xraw, const float* __restrict__ W1f,
                      const int* __restrict__ flag, float* __restrict__ h) {
    __shared__ float w[INDIM * DIM];
    __shared__ float xsh[8 * INDIM];
    int t = threadIdx.x;
    for (int i = t; i < INDIM * DIM; i += 256) w[i] = W1f[i];
    if (flag[0]) {
        const unsigned int* xsrc = (const unsigned int*)((const unsigned short*)xraw
                                   + (size_t)blockIdx.x * 8 * INDIM);
        for (int i = t; i < 512; i += 256) {
            unsigned u = xsrc[i];
            xsh[2 * i]     = __uint_as_float(u << 16);
            xsh[2 * i + 1] = __uint_as_float(u & 0xFFFF0000u);
        }
    } else {
        const float4* xsrc = (const float4*)((const float*)xraw + (size_t)blockIdx.x * 8 * INDIM);
        float4* xdst = (float4*)xsh;
        for (int i = t; i < 256; i += 256) xdst[i] = xsrc[i];
    }
    __syncthreads();
    int ln = t >> 5, c = t & 31;
    const float* xr = xsh + ln * INDIM;
    float acc = 0.f;
    #pragma unroll 8
    for (int j = 0; j < INDIM; j++) acc += xr[j] * w[j * DIM + c];
    h[(size_t)blockIdx.x * 256 + t] = acc;
}

__global__ void k_mm32(const float* __restrict__ xin, const float* __restrict__ W,
                       const float* __restrict__ W4, float* __restrict__ h,
                       float* __restrict__ h4) {
    __shared__ float w[DIM * DIM];
    __shared__ float w4s[DIM];
    __shared__ float xsh[8 * DIM];
    int t = threadIdx.x;
    for (int i = t; i < DIM * DIM; i += 256) w[i] = W[i];
    if (W4 && t < DIM) w4s[t] = W4[t];
    for (int i = t; i < 8 * DIM; i += 256) xsh[i] = xin[(size_t)blockIdx.x * 256 + i];
    __syncthreads();
    int ln = t >> 5, c = t & 31;
    const float* xr = xsh + ln * DIM;
    float acc = 0.f;
    #pragma unroll
    for (int j = 0; j < DIM; j++) acc += xr[j] * w[j * DIM + c];
    h[(size_t)blockIdx.x * 256 + t] = acc;
    if (W4 && c == 0) {
        float a4 = 0.f;
        #pragma unroll
        for (int j = 0; j < DIM; j++) a4 += xr[j] * w4s[j];
        h4[blockIdx.x * 8 + ln] = a4;
    }
}

// per node: 32 lanes = channels; depth-2 quad pipeline (8 row-gathers in flight).
__global__ void k_gather(const float* __restrict__ h, const float* __restrict__ h4,
                         const int* __restrict__ csr_src, const float* __restrict__ csr_cf,
                         const int* __restrict__ row_off, const int* __restrict__ degi,
                         const float* __restrict__ dinv, const float* __restrict__ bias,
                         const float* __restrict__ b4,
                         float* __restrict__ xout, float* __restrict__ x4out) {
    int t = threadIdx.x;
    int node = blockIdx.x * 8 + (t >> 5);
    int lane = t & 31;
    int start = row_off[node];           // multiple of 4 -> 16B aligned
    int cnt   = degi[node];
    int iters = (cnt + 3) >> 2;
    const int4*   ip = (const int4*)(csr_src + start);
    const float4* cp = (const float4*)(csr_cf + start);
    float acc = 0.f;
    if (iters > 0) {
        int4   iq[2];
        float4 cq[2];
        iq[0] = ip[0]; cq[0] = cp[0];
        if (iters > 1) { iq[1] = ip[1]; cq[1] = cp[1]; }
        for (int k = 0; k < iters; k++) {
            int4   ic = iq[k & 1];
            float4 cc = cq[k & 1];
            int nb = k + 2;
            if (nb < iters) { iq[k & 1] = ip[nb]; cq[k & 1] = cp[nb]; }
            acc += h[(size_t)ic.x * DIM + lane] * cc.x;
            acc += h[(size_t)ic.y * DIM + lane] * cc.y;
            acc += h[(size_t)ic.z * DIM + lane] * cc.z;
            acc += h[(size_t)ic.w * DIM + lane] * cc.w;
        }
    }
    float di = dinv[node];
    float outv = tanhf(acc + h[(size_t)node * DIM + lane] * di + bias[lane]);
    xout[(size_t)node * DIM + lane] = outv;
    if (h4) {
        int cntp = iters << 2;
        float a4 = 0.f;
        for (int ee = lane; ee < cntp; ee += 32)
            a4 += h4[csr_src[start + ee]] * csr_cf[start + ee];
        for (int off = 16; off > 0; off >>= 1) a4 += __shfl_xor(a4, off, 32);
        if (lane == 0) x4out[node] = tanhf(a4 + h4[node] * di + b4[0]);
    }
}

// ---------------- sort pooling ----------------
__global__ void k_sortpool(const float* __restrict__ x4, int* __restrict__ sel) {
    __shared__ unsigned long long keys[512];
    int g = blockIdx.x, t = threadIdx.x;
    for (int i = t; i < 512; i += 256) {
        unsigned long long kk = 0xFFFFFFFFFFFFFFFFULL;
        if (i < NPER) {
            unsigned u = __float_as_uint(x4[g * NPER + i]);
            u = (u & 0x80000000u) ? ~u : (u | 0x80000000u);
            kk = ((unsigned long long)(~u) << 32) | (unsigned)i;
        }
        keys[i] = kk;
    }
    __syncthreads();
    for (int k = 2; k <= 512; k <<= 1)
        for (int j = k >> 1; j > 0; j >>= 1) {
            for (int i = t; i < 512; i += 256) {
                int l = i ^ j;
                if (l > i) {
                    unsigned long long a = keys[i], b = keys[l];
                    bool asc = ((i & k) == 0);
                    if ((a > b) == asc) { keys[i] = b; keys[l] = a; }
                }
            }
            __syncthreads();
        }
    for (int i = t; i < KTOP; i += 256)
        sel[g * KTOP + i] = g * NPER + (int)(unsigned)(keys[i] & 0xFFFFFFFFu);
}

// ---------------- conv1 (per-slot linear) + maxpool ----------------
__global__ void k_conv1pool(const float* __restrict__ x1, const float* __restrict__ x2,
                            const float* __restrict__ x3, const float* __restrict__ x4,
                            const int* __restrict__ sel, const float* __restrict__ cw1f,
                            const float* __restrict__ cb1f, float* __restrict__ p1g) {
    __shared__ __align__(16) float xs[32 * 100];   // [q][k]
    __shared__ __align__(16) float ws[32 * 128];   // [q][c]
    __shared__ int nsh[KTOP];
    int g = blockIdx.x, t = threadIdx.x;
    if (t < KTOP) nsh[t] = sel[g * KTOP + t];
    int ct = (t & 31) * 4;
    int kbase = (t >> 5) * 4;           // kt for set s = kbase + 32*s
    int nset = (t < 32) ? 4 : 3;        // tiles t+256*s, valid while < 800
    float acc[4][4][4] = {};            // [set][k-off][c-off]
    for (int ch = 0; ch < 3; ch++) {
        const float* arr = (ch == 0) ? x1 : (ch == 1) ? x2 : x3;
        __syncthreads();
        for (int i = t; i < 3200; i += 256) {       // q fastest → coalesced node rows
            int q = i & 31, k = i >> 5;
            xs[q * 100 + k] = arr[(size_t)nsh[k] * 32 + q];
        }
        for (int i = t; i < 4096; i += 256) {       // c fastest → conflict-free LDS write
            int c = i & 127, q = i >> 7;
            ws[q * 128 + c] = cw1f[c * TOTALC + ch * 32 + q];
        }
        __syncthreads();
        for (int q = 0; q < 32; q++) {
            float4 wv = *(const float4*)&ws[q * 128 + ct];
            #pragma unroll
            for (int s = 0; s < 4; s++) {
                if (s >= nset) break;
                float4 xv = *(const float4*)&xs[q * 100 + kbase + 32 * s];
                float xa[4] = { xv.x, xv.y, xv.z, xv.w };
                float wa[4] = { wv.x, wv.y, wv.z, wv.w };
                #pragma unroll
                for (int a = 0; a < 4; a++)
                    #pragma unroll
                    for (int b = 0; b < 4; b++)
                        acc[s][a][b] += xa[a] * wa[b];
            }
        }
    }
    {   // tail channel q = 96 (x4)
        float wa[4];
        #pragma unroll
        for (int b = 0; b < 4; b++) wa[b] = cw1f[(ct + b) * TOTALC + 96];
        for (int s = 0; s < nset; s++) {
            int kt = kbase + 32 * s;
            #pragma unroll
            for (int a = 0; a < 4; a++) {
                float xv = x4[nsh[kt + a]];
                #pragma unroll
                for (int b = 0; b < 4; b++) acc[s][a][b] += xv * wa[b];
            }
        }
    }
    for (int s = 0; s < nset; s++) {
        int kt = kbase + 32 * s;
        int jbase = kt >> 1;
        #pragma unroll
        for (int b = 0; b < 4; b++) {
            float bias = cb1f[ct + b];
            float m0 = fmaxf(fmaxf(acc[s][0][b], acc[s][1][b]) + bias, 0.f);
            float m1 = fmaxf(fmaxf(acc[s][2][b], acc[s][3][b]) + bias, 0.f);
            p1g[((size_t)g * 128 + ct + b) * 50 + jbase]     = m0;
            p1g[((size_t)g * 128 + ct + b) * 50 + jbase + 1] = m1;
        }
    }
}

__global__ void k_w2t(const float* __restrict__ cw2f, float* __restrict__ w2t) {
    int i = blockIdx.x * 256 + threadIdx.x;
    if (i < 64 * 128 * 5) {
        int o = i / 640, r = i % 640, c = r / 5, q = r % 5;
        w2t[(c * 5 + q) * 64 + o] = cw2f[i];
    }
}

// ---------------- conv2 + fc1 + fc3 + log_softmax (1024 threads) ----------------
__global__ __launch_bounds__(1024) void
k_conv2fc(const float* __restrict__ p1g, const float* __restrict__ w2t,
          const float* __restrict__ cb2f,
          const float* __restrict__ fw1t, const float* __restrict__ fb1f,
          const float* __restrict__ fw3f, const float* __restrict__ fb3f,
          const int* __restrict__ flag, void* __restrict__ outp) {
    __shared__ __align__(16) float p1s[128 * 52];   // padded rows for aligned float4 windows
    __shared__ float flat[64 * 46];
    __shared__ float hpart[1024];
    __shared__ float hsh[128];
    int g = blockIdx.x, t = threadIdx.x;
    for (int i = t; i < 128 * 50; i += 1024) {
        int c = i / 50, p = i % 50;
        p1s[c * 52 + p] = p1g[(size_t)g * 6400 + i];
    }
    for (int i = t; i < 128 * 2; i += 1024) {       // zero pad cols 50,51
        int c = i >> 1;
        p1s[c * 52 + 50 + (i & 1)] = 0.f;
    }
    for (int i = t; i < 2944; i += 1024) flat[i] = 0.f;
    __syncthreads();
    {   // conv2: o = lane; (ph, c-eighth) over 16 segments; in-register sliding window
        int o = t & 63;
        int seg = t >> 6;                // 0..15
        int ph = seg & 1, c8 = seg >> 1; // c8: 0..7
        int p0 = ph ? 24 : 0;
        int np = ph ? 22 : 24;
        float acc[24];
        #pragma unroll
        for (int p = 0; p < 24; p++) acc[p] = 0.f;
        int cbeg = c8 * 16;
        for (int c = cbeg; c < cbeg + 16; c++) {
            float win[28];
            const float4* wsrc = (const float4*)&p1s[c * 52 + p0];
            #pragma unroll
            for (int v = 0; v < 7; v++) {
                float4 f = wsrc[v];
                win[4 * v] = f.x; win[4 * v + 1] = f.y; win[4 * v + 2] = f.z; win[4 * v + 3] = f.w;
            }
            #pragma unroll
            for (int q = 0; q < 5; q++) {
                float wv = w2t[(c * 5 + q) * 64 + o];
                #pragma unroll
                for (int p = 0; p < 24; p++) acc[p] += win[p + q] * wv;
            }
        }
        for (int p = 0; p < np; p++) atomicAdd(&flat[o * 46 + p0 + p], acc[p]);
    }
    __syncthreads();
    for (int i = t; i < 2944; i += 1024) {
        int o = i / 46;
        flat[i] = fmaxf(flat[i] + cb2f[o], 0.f);
    }
    __syncthreads();
    {   // fc1: gg = t&127 output, slice = t>>7 covers 368 d's; fw1t coalesced over gg
        int gg = t & 127, slice = t >> 7;
        const float* fl = flat + slice * 368;
        const float* wp = fw1t + (size_t)slice * 368 * 128 + gg;
        float a = 0.f;
        #pragma unroll 4
        for (int d = 0; d < 368; d++) a += fl[d] * wp[(size_t)d * 128];
        hpart[t] = a;
    }
    __syncthreads();
    if (t < 128) {
        float s = fb1f[t];
        #pragma unroll
        for (int s2 = 0; s2 < 8; s2++) s += hpart[t + 128 * s2];
        hsh[t] = fmaxf(s, 0.f);
    }
    __syncthreads();
    if (t == 0) {
        float l0 = fb3f[0], l1 = fb3f[1];
        for (int j = 0; j < 128; j++) {
            l0 += hsh[j] * fw3f[j];
            l1 += hsh[j] * fw3f[128 + j];
        }
        float m = fmaxf(l0, l1);
        float lse = m + logf(expf(l0 - m) + expf(l1 - m));
        if (flag[0]) {
            unsigned short* ob = (unsigned short*)outp;
            ob[g * 2 + 0] = f2bf(l0 - lse);
            ob[g * 2 + 1] = f2bf(l1 - lse);
        } else {
            float* of = (float*)outp;
            of[g * 2 + 0] = l0 - lse;
            of[g * 2 + 1] = l1 - lse;
        }
    }
}

// ---------------- launch ----------------

extern "C" void kernel_launch(void* const* d_in, const int* in_sizes, int n_in,
                              void* d_out, int out_size, void* d_ws, size_t ws_size,
                              hipStream_t stream) {
    const void* x  = d_in[0];
    const int* ei  = (const int*)d_in[1];
    // d_in[2] = batch (arange/400, unused)

    char* p = (char*)d_ws;
    auto alloc = [&](size_t bytes) -> void* {
        void* r = (void*)p;
        p += (bytes + 255) & ~(size_t)255;
        return r;
    };
    int*      flag    = (int*)alloc(256);
    float*    wcv     = (float*)alloc((size_t)OW_TOT * 4);
    float*    fw1t    = (float*)alloc((size_t)376832 * 4);
    int*      ghist   = (int*)alloc((size_t)NBUCK * NCHUNK * 4);
    int*      bcnt    = (int*)alloc(1024 * 4);
    int*      boff    = (int*)alloc(1024 * 4);
    int*      bsums   = (int*)alloc(512 * 4);
    int*      degi    = (int*)alloc((size_t)NNODES * 4);
    int*      row_off = (int*)alloc((size_t)NNODES * 4);
    float*    dis     = (float*)alloc((size_t)NNODES * 4);
    float*    dinv    = (float*)alloc((size_t)NNODES * 4);
    unsigned* staged  = (unsigned*)alloc((size_t)NEDGES * 4);
    int*      csr_src = (int*)alloc((size_t)NPADE * 4);
    float*    csr_cf  = (float*)alloc((size_t)NPADE * 4);
    float*    hbuf    = (float*)alloc((size_t)NNODES * DIM * 4);
    float*    h4buf   = (float*)alloc((size_t)NNODES * 4);
    float*    x1      = (float*)alloc((size_t)NNODES * DIM * 4);
    float*    x2      = (float*)alloc((size_t)NNODES * DIM * 4);
    float*    x3      = (float*)alloc((size_t)NNODES * DIM * 4);
    float*    x4      = (float*)alloc((size_t)NNODES * 4);
    int*      sel     = (int*)alloc((size_t)NGRAPH * KTOP * 4);
    float*    p1g     = (float*)alloc((size_t)NGRAPH * 128 * 50 * 4);
    float*    w2t     = (float*)alloc((size_t)64 * 128 * 5 * 4);
    (void)in_sizes; (void)n_in; (void)out_size; (void)ws_size;

    k_detect<<<1, 256, 0, stream>>>((const unsigned int*)x, flag);
    Srcs sr;
    for (int i = 0; i < 16; i++) sr.p[i] = d_in[3 + i];
    k_convert<<<(OW_TOT + 255) / 256, 256, 0, stream>>>(sr, wcv, flag);
    k_w1t    <<<1472, 256, 0, stream>>>(wcv + OW_FW1, fw1t);

    k_hist     <<<NCHUNK, 256, 0, stream>>>(ei, ghist);
    k_scanChunk<<<NBUCK, 1024, 0, stream>>>(ghist, bcnt);
    k_scanB    <<<1, 1024, 0, stream>>>(bcnt, boff);
    k_binwrite <<<NCHUNK, 256, 0, stream>>>(ei, boff, ghist, staged);
    k_nodecnt  <<<NBUCK, 256, 0, stream>>>(staged, boff, degi);
    k_nodeprep <<<391, 256, 0, stream>>>(degi, dis, dinv);
    k_bsum     <<<391, 256, 0, stream>>>(degi, bsums);
    k_scanb    <<<1, 512, 0, stream>>>(bsums, 391);
    k_scanf    <<<391, 256, 0, stream>>>(degi, bsums, row_off);
    k_csrfix   <<<NBUCK, 256, 0, stream>>>(staged, boff, row_off, dis, csr_src, csr_cf);

    k_mm1   <<<12500, 256, 0, stream>>>(x, wcv + OW_W1, flag, hbuf);
    k_gather<<<12500, 256, 0, stream>>>(hbuf, nullptr, csr_src, csr_cf, row_off, degi, dinv,
                                        wcv + OW_B1, nullptr, x1, nullptr);
    k_mm32  <<<12500, 256, 0, stream>>>(x1, wcv + OW_W2, nullptr, hbuf, nullptr);
    k_gather<<<12500, 256, 0, stream>>>(hbuf, nullptr, csr_src, csr_cf, row_off, degi, dinv,
                                        wcv + OW_B2, nullptr, x2, nullptr);
    k_mm32  <<<12500, 256, 0, stream>>>(x2, wcv + OW_W3, wcv + OW_W4, hbuf, h4buf);
    k_gather<<<12500, 256, 0, stream>>>(hbuf, h4buf, csr_src, csr_cf, row_off, degi, dinv,
                                        wcv + OW_B3, wcv + OW_B4, x3, x4);

    k_sortpool <<<NGRAPH, 256, 0, stream>>>(x4, sel);
    k_conv1pool<<<NGRAPH, 256, 0, stream>>>(x1, x2, x3, x4, sel, wcv + OW_CW1, wcv + OW_CB1, p1g);
    k_w2t      <<<160, 256, 0, stream>>>(wcv + OW_CW2, w2t);
    k_conv2fc  <<<NGRAPH, 1024, 0, stream>>>(p1g, w2t, wcv + OW_CB2, fw1t, wcv + OW_FB1,
                                             wcv + OW_FW3, wcv + OW_FB3, flag, d_out);
}

// Round 7
// 699.225 us; speedup vs baseline: 1.6607x; 1.6607x over previous
//
#include <hip/hip_runtime.h>
#include <hip/hip_bf16.h>

#define NNODES 100000
#define NEDGES 3200000
#define NPADE  3600000  // NEDGES + 4*NNODES worst-case row padding
#define NPER   400
#define NGRAPH 250
#define KTOP   100
#define DIM    32
#define INDIM  128
#define TOTALC 97
#define BSHIFT 7
#define BNODES 128
#define NBUCK  782   // ceil(100000/128)
#define NCHUNK 1024
#define CHSZ   3125  // NEDGES / NCHUNK

__device__ __forceinline__ float bf(unsigned short u) {
    return __uint_as_float(((unsigned)u) << 16);
}
__device__ __forceinline__ unsigned short f2bf(float f) {
    unsigned u = __float_as_uint(f);
    unsigned r = ((u >> 16) & 1u) + 0x7FFFu;   // round-to-nearest-even
    return (unsigned short)((u + r) >> 16);
}

// converted-weights fp32 layout in ws (element offsets, padded to 8)
#define OW_W1   0
#define OW_B1   4096
#define OW_W2   4128
#define OW_B2   5152
#define OW_W3   5184
#define OW_B3   6208
#define OW_W4   6240
#define OW_B4   6272
#define OW_CW1  6280
#define OW_CB1  18696
#define OW_CW2  18824
#define OW_CB2  59784
#define OW_FW1  59848
#define OW_FB1  436680
#define OW_FW3  436808
#define OW_FB3  437064
#define OW_TOT  437072

// ---------------- dtype detect + weight convert ----------------

__global__ void k_detect(const unsigned int* __restrict__ xw, int* __restrict__ flag) {
    __shared__ int cnt[256];
    int t = threadIdx.x, c = 0;
    for (int i = t; i < 4096; i += 256) {
        unsigned e = (xw[i] >> 23) & 0xFFu;
        if (e >= 100u && e <= 150u) c++;
    }
    cnt[t] = c;
    __syncthreads();
    for (int off = 128; off > 0; off >>= 1) {
        if (t < off) cnt[t] += cnt[t + off];
        __syncthreads();
    }
    if (t == 0) flag[0] = (cnt[0] < 2048) ? 1 : 0;   // 1 = inputs are bf16
}

struct Srcs { const void* p[16]; };

__global__ void k_convert(Srcs sr, float* __restrict__ dst, const int* __restrict__ flag) {
    const int st[16] = {OW_W1, OW_B1, OW_W2, OW_B2, OW_W3, OW_B3, OW_W4, OW_B4,
                        OW_CW1, OW_CB1, OW_CW2, OW_CB2, OW_FW1, OW_FB1, OW_FW3, OW_FB3};
    const int nn[16] = {4096, 32, 1024, 32, 1024, 32, 32, 1,
                        12416, 128, 40960, 64, 376832, 128, 256, 2};
    int idx = blockIdx.x * 256 + threadIdx.x;
    if (idx >= OW_TOT) return;
    int isb = flag[0];
    #pragma unroll
    for (int s = 0; s < 16; s++) {
        if (idx >= st[s] && idx < st[s] + nn[s]) {
            int l = idx - st[s];
            dst[idx] = isb ? bf(((const unsigned short*)sr.p[s])[l])
                           : ((const float*)sr.p[s])[l];
        }
    }
}

// fw1 [128][2944] -> fw1t [2944][128] (one-time, L2-resident)
__global__ void k_w1t(const float* __restrict__ fw1f, float* __restrict__ fw1t) {
    int i = blockIdx.x * 256 + threadIdx.x;
    if (i < 376832) {
        int j = i / 2944, d = i % 2944;
        fw1t[d * 128 + j] = fw1f[i];
    }
}

// ---------------- graph prep: contention-free counting sort ----------------

__global__ __launch_bounds__(256) void k_hist(const int* __restrict__ ei, int* __restrict__ ghist) {
    __shared__ int h[NBUCK];
    int c = blockIdx.x, t = threadIdx.x;
    for (int i = t; i < NBUCK; i += 256) h[i] = 0;
    __syncthreads();
    int base = c * CHSZ;
    for (int e = base + t; e < base + CHSZ; e += 256)
        atomicAdd(&h[ei[NEDGES + e] >> BSHIFT], 1);
    __syncthreads();
    for (int i = t; i < NBUCK; i += 256) ghist[i * NCHUNK + c] = h[i];
}

__global__ __launch_bounds__(1024) void k_scanChunk(int* __restrict__ ghist, int* __restrict__ bcnt) {
    __shared__ int s[NCHUNK];
    int b = blockIdx.x, t = threadIdx.x;
    int v = ghist[b * NCHUNK + t];
    s[t] = v;
    __syncthreads();
    for (int o = 1; o < NCHUNK; o <<= 1) {
        int u = (t >= o) ? s[t - o] : 0;
        __syncthreads();
        s[t] += u;
        __syncthreads();
    }
    ghist[b * NCHUNK + t] = s[t] - v;   // exclusive within bucket
    if (t == NCHUNK - 1) bcnt[b] = s[t];
}

__global__ void k_scanB(const int* __restrict__ bcnt, int* __restrict__ boff) {
    __shared__ int s[1024];
    int t = threadIdx.x;
    int v = (t < NBUCK) ? bcnt[t] : 0;
    s[t] = v;
    __syncthreads();
    for (int o = 1; o < 1024; o <<= 1) {
        int u = (t >= o) ? s[t - o] : 0;
        __syncthreads();
        s[t] += u;
        __syncthreads();
    }
    if (t < NBUCK) boff[t] = s[t] - v;   // exclusive
}

__global__ __launch_bounds__(256) void k_binwrite(const int* __restrict__ ei, const int* __restrict__ boff,
                           const int* __restrict__ ghist, unsigned* __restrict__ staged) {
    __shared__ int cur[NBUCK];
    int c = blockIdx.x, t = threadIdx.x;
    for (int i = t; i < NBUCK; i += 256) cur[i] = boff[i] + ghist[i * NCHUNK + c];
    __syncthreads();
    int base = c * CHSZ;
    for (int e = base + t; e < base + CHSZ; e += 256) {
        int s = ei[e], d = ei[NEDGES + e];
        int b = d >> BSHIFT;
        int pos = atomicAdd(&cur[b], 1);
        staged[pos] = ((unsigned)(d & (BNODES - 1)) << 17) | (unsigned)s;
    }
}

__global__ __launch_bounds__(256) void k_nodecnt(const unsigned* __restrict__ staged,
                          const int* __restrict__ boff, int* __restrict__ degi) {
    __shared__ int cnt[BNODES];
    int b = blockIdx.x, t = threadIdx.x;
    if (t < BNODES) cnt[t] = 0;
    __syncthreads();
    int s0 = boff[b];
    int s1 = (b + 1 < NBUCK) ? boff[b + 1] : NEDGES;
    for (int i = s0 + t; i < s1; i += 256)
        atomicAdd(&cnt[staged[i] >> 17], 1);
    __syncthreads();
    int n0 = b << BSHIFT;
    int nn = min(BNODES, NNODES - n0);
    if (t < nn) degi[n0 + t] = cnt[t];
}

__global__ void k_nodeprep(const int* __restrict__ degi, float* __restrict__ dis,
                           float* __restrict__ dinv) {
    int i = blockIdx.x * 256 + threadIdx.x;
    if (i < NNODES) {
        float d = (float)(degi[i] + 1);
        dis[i]  = rsqrtf(d);
        dinv[i] = 1.0f / d;
    }
}

// scans below use PADDED degree (rounded up to 4) so CSR rows are 16B-aligned
__global__ void k_bsum(const int* __restrict__ degi, int* __restrict__ bsums) {
    __shared__ int s[256];
    int t = threadIdx.x;
    int i = blockIdx.x * 256 + t;
    s[t] = (i < NNODES) ? ((degi[i] + 3) & ~3) : 0;
    __syncthreads();
    for (int off = 128; off > 0; off >>= 1) {
        if (t < off) s[t] += s[t + off];
        __syncthreads();
    }
    if (t == 0) bsums[blockIdx.x] = s[0];
}

__global__ void k_scanb(int* __restrict__ bsums, int nb) {
    __shared__ int s[512];
    int t = threadIdx.x;
    int v = (t < nb) ? bsums[t] : 0;
    s[t] = v;
    __syncthreads();
    for (int off = 1; off < 512; off <<= 1) {
        int u = (t >= off) ? s[t - off] : 0;
        __syncthreads();
        s[t] += u;
        __syncthreads();
    }
    if (t < nb) bsums[t] = s[t] - v;   // exclusive
}

__global__ void k_scanf(const int* __restrict__ degi, const int* __restrict__ bsums,
                        int* __restrict__ row_off) {
    __shared__ int s[256];
    int t = threadIdx.x;
    int i = blockIdx.x * 256 + t;
    int v = (i < NNODES) ? ((degi[i] + 3) & ~3) : 0;
    s[t] = v;
    __syncthreads();
    for (int off = 1; off < 256; off <<= 1) {
        int u = (t >= off) ? s[t - off] : 0;
        __syncthreads();
        s[t] += u;
        __syncthreads();
    }
    if (i < NNODES) row_off[i] = bsums[blockIdx.x] + s[t] - v;  // exclusive
}

__global__ __launch_bounds__(256) void k_csrfix(const unsigned* __restrict__ staged,
                         const int* __restrict__ boff, const int* __restrict__ row_off,
                         const float* __restrict__ dis,
                         int* __restrict__ csr_src, float* __restrict__ csr_cf) {
    __shared__ int cnt[BNODES];
    __shared__ int rofs[BNODES];
    __shared__ float disl[BNODES];
    int b = blockIdx.x, t = threadIdx.x;
    int n0 = b << BSHIFT;
    int nn = min(BNODES, NNODES - n0);
    if (t < BNODES) {
        cnt[t]  = 0;
        rofs[t] = (t < nn) ? row_off[n0 + t] : 0;
        disl[t] = (t < nn) ? dis[n0 + t] : 0.f;
    }
    __syncthreads();
    int s0 = boff[b];
    int s1 = (b + 1 < NBUCK) ? boff[b + 1] : NEDGES;
    for (int i = s0 + t; i < s1; i += 256) {
        unsigned rec = staged[i];
        int dl = rec >> 17, s = rec & 0x1FFFF;
        int r = atomicAdd(&cnt[dl], 1);
        int slot = rofs[dl] + r;
        csr_src[slot] = s;
        csr_cf[slot]  = dis[s] * disl[dl];
    }
    __syncthreads();
    if (t < nn) {   // inert pad entries: src=0 (harmless read), cf=0
        int d = cnt[t], dp = (d + 3) & ~3;
        for (int s2 = d; s2 < dp; s2++) {
            csr_src[rofs[t] + s2] = 0;
            csr_cf[rofs[t] + s2]  = 0.f;
        }
    }
}

// ---------------- GCN dense parts ----------------

__global__ void k_mm1(const void* __restrict__ xraw, const float* __restrict__ W1f,
                      const int* __restrict__ flag, float* __restrict__ h) {
    __shared__ float w[INDIM * DIM];
    __shared__ float xsh[8 * INDIM];
    int t = threadIdx.x;
    for (int i = t; i < INDIM * DIM; i += 256) w[i] = W1f[i];
    if (flag[0]) {
        const unsigned int* xsrc = (const unsigned int*)((const unsigned short*)xraw
                                   + (size_t)blockIdx.x * 8 * INDIM);
        for (int i = t; i < 512; i += 256) {
            unsigned u = xsrc[i];
            xsh[2 * i]     = __uint_as_float(u << 16);
            xsh[2 * i + 1] = __uint_as_float(u & 0xFFFF0000u);
        }
    } else {
        const float4* xsrc = (const float4*)((const float*)xraw + (size_t)blockIdx.x * 8 * INDIM);
        float4* xdst = (float4*)xsh;
        for (int i = t; i < 256; i += 256) xdst[i] = xsrc[i];
    }
    __syncthreads();
    int ln = t >> 5, c = t & 31;
    const float* xr = xsh + ln * INDIM;
    float acc = 0.f;
    #pragma unroll 8
    for (int j = 0; j < INDIM; j++) acc += xr[j] * w[j * DIM + c];
    h[(size_t)blockIdx.x * 256 + t] = acc;
}

__global__ void k_mm32(const float* __restrict__ xin, const float* __restrict__ W,
                       const float* __restrict__ W4, float* __restrict__ h,
                       float* __restrict__ h4) {
    __shared__ float w[DIM * DIM];
    __shared__ float w4s[DIM];
    __shared__ float xsh[8 * DIM];
    int t = threadIdx.x;
    for (int i = t; i < DIM * DIM; i += 256) w[i] = W[i];
    if (W4 && t < DIM) w4s[t] = W4[t];
    for (int i = t; i < 8 * DIM; i += 256) xsh[i] = xin[(size_t)blockIdx.x * 256 + i];
    __syncthreads();
    int ln = t >> 5, c = t & 31;
    const float* xr = xsh + ln * DIM;
    float acc = 0.f;
    #pragma unroll
    for (int j = 0; j < DIM; j++) acc += xr[j] * w[j * DIM + c];
    h[(size_t)blockIdx.x * 256 + t] = acc;
    if (W4 && c == 0) {
        float a4 = 0.f;
        #pragma unroll
        for (int j = 0; j < DIM; j++) a4 += xr[j] * w4s[j];
        h4[blockIdx.x * 8 + ln] = a4;
    }
}

// per node: 32 lanes = channels; 4-wide vectorized CSR with next-quad prefetch.
// NOTE: prefetch uses NAMED registers only — a [k&1]-indexed array here gets
// lowered to a 64KB LDS scratch block (R6: occupancy 74->19%, 2.2x slower).
__global__ void k_gather(const float* __restrict__ h, const float* __restrict__ h4,
                         const int* __restrict__ csr_src, const float* __restrict__ csr_cf,
                         const int* __restrict__ row_off, const int* __restrict__ degi,
                         const float* __restrict__ dinv, const float* __restrict__ bias,
                         const float* __restrict__ b4,
                         float* __restrict__ xout, float* __restrict__ x4out) {
    int t = threadIdx.x;
    int node = blockIdx.x * 8 + (t >> 5);
    int lane = t & 31;
    int start = row_off[node];           // multiple of 4 -> 16B aligned
    int cnt   = degi[node];
    int iters = (cnt + 3) >> 2;
    const int4*   ip = (const int4*)(csr_src + start);
    const float4* cp = (const float4*)(csr_cf + start);
    float acc = 0.f;
    if (iters > 0) {
        int4   i0 = ip[0];
        float4 c0 = cp[0];
        for (int k = 1; k < iters; k++) {
            int4   i1 = ip[k];           // prefetch next quad (breaks idx->row chain)
            float4 c1 = cp[k];
            acc += h[(size_t)i0.x * DIM + lane] * c0.x;
            acc += h[(size_t)i0.y * DIM + lane] * c0.y;
            acc += h[(size_t)i0.z * DIM + lane] * c0.z;
            acc += h[(size_t)i0.w * DIM + lane] * c0.w;
            i0 = i1; c0 = c1;
        }
        acc += h[(size_t)i0.x * DIM + lane] * c0.x;
        acc += h[(size_t)i0.y * DIM + lane] * c0.y;
        acc += h[(size_t)i0.z * DIM + lane] * c0.z;
        acc += h[(size_t)i0.w * DIM + lane] * c0.w;
    }
    float di = dinv[node];
    float outv = tanhf(acc + h[(size_t)node * DIM + lane] * di + bias[lane]);
    xout[(size_t)node * DIM + lane] = outv;
    if (h4) {
        int cntp = iters << 2;
        float a4 = 0.f;
        for (int ee = lane; ee < cntp; ee += 32)
            a4 += h4[csr_src[start + ee]] * csr_cf[start + ee];
        for (int off = 16; off > 0; off >>= 1) a4 += __shfl_xor(a4, off, 32);
        if (lane == 0) x4out[node] = tanhf(a4 + h4[node] * di + b4[0]);
    }
}

// ---------------- sort pooling ----------------
__global__ void k_sortpool(const float* __restrict__ x4, int* __restrict__ sel) {
    __shared__ unsigned long long keys[512];
    int g = blockIdx.x, t = threadIdx.x;
    for (int i = t; i < 512; i += 256) {
        unsigned long long kk = 0xFFFFFFFFFFFFFFFFULL;
        if (i < NPER) {
            unsigned u = __float_as_uint(x4[g * NPER + i]);
            u = (u & 0x80000000u) ? ~u : (u | 0x80000000u);
            kk = ((unsigned long long)(~u) << 32) | (unsigned)i;
        }
        keys[i] = kk;
    }
    __syncthreads();
    for (int k = 2; k <= 512; k <<= 1)
        for (int j = k >> 1; j > 0; j >>= 1) {
            for (int i = t; i < 512; i += 256) {
                int l = i ^ j;
                if (l > i) {
                    unsigned long long a = keys[i], b = keys[l];
                    bool asc = ((i & k) == 0);
                    if ((a > b) == asc) { keys[i] = b; keys[l] = a; }
                }
            }
            __syncthreads();
        }
    for (int i = t; i < KTOP; i += 256)
        sel[g * KTOP + i] = g * NPER + (int)(unsigned)(keys[i] & 0xFFFFFFFFu);
}

// ---------------- conv1 (per-slot linear) + maxpool ----------------
__global__ void k_conv1pool(const float* __restrict__ x1, const float* __restrict__ x2,
                            const float* __restrict__ x3, const float* __restrict__ x4,
                            const int* __restrict__ sel, const float* __restrict__ cw1f,
                            const float* __restrict__ cb1f, float* __restrict__ p1g) {
    __shared__ __align__(16) float xs[32 * 100];   // [q][k]
    __shared__ __align__(16) float ws[32 * 128];   // [q][c]
    __shared__ int nsh[KTOP];
    int g = blockIdx.x, t = threadIdx.x;
    if (t < KTOP) nsh[t] = sel[g * KTOP + t];
    int ct = (t & 31) * 4;
    int kbase = (t >> 5) * 4;           // kt for set s = kbase + 32*s
    int nset = (t < 32) ? 4 : 3;        // tiles t+256*s, valid while < 800
    float acc[4][4][4] = {};            // [set][k-off][c-off]
    for (int ch = 0; ch < 3; ch++) {
        const float* arr = (ch == 0) ? x1 : (ch == 1) ? x2 : x3;
        __syncthreads();
        for (int i = t; i < 3200; i += 256) {       // q fastest → coalesced node rows
            int q = i & 31, k = i >> 5;
            xs[q * 100 + k] = arr[(size_t)nsh[k] * 32 + q];
        }
        for (int i = t; i < 4096; i += 256) {       // c fastest → conflict-free LDS write
            int c = i & 127, q = i >> 7;
            ws[q * 128 + c] = cw1f[c * TOTALC + ch * 32 + q];
        }
        __syncthreads();
        for (int q = 0; q < 32; q++) {
            float4 wv = *(const float4*)&ws[q * 128 + ct];
            #pragma unroll
            for (int s = 0; s < 4; s++) {
                if (s >= nset) break;
                float4 xv = *(const float4*)&xs[q * 100 + kbase + 32 * s];
                float xa[4] = { xv.x, xv.y, xv.z, xv.w };
                float wa[4] = { wv.x, wv.y, wv.z, wv.w };
                #pragma unroll
                for (int a = 0; a < 4; a++)
                    #pragma unroll
                    for (int b = 0; b < 4; b++)
                        acc[s][a][b] += xa[a] * wa[b];
            }
        }
    }
    {   // tail channel q = 96 (x4)
        float wa[4];
        #pragma unroll
        for (int b = 0; b < 4; b++) wa[b] = cw1f[(ct + b) * TOTALC + 96];
        for (int s = 0; s < nset; s++) {
            int kt = kbase + 32 * s;
            #pragma unroll
            for (int a = 0; a < 4; a++) {
                float xv = x4[nsh[kt + a]];
                #pragma unroll
                for (int b = 0; b < 4; b++) acc[s][a][b] += xv * wa[b];
            }
        }
    }
    for (int s = 0; s < nset; s++) {
        int kt = kbase + 32 * s;
        int jbase = kt >> 1;
        #pragma unroll
        for (int b = 0; b < 4; b++) {
            float bias = cb1f[ct + b];
            float m0 = fmaxf(fmaxf(acc[s][0][b], acc[s][1][b]) + bias, 0.f);
            float m1 = fmaxf(fmaxf(acc[s][2][b], acc[s][3][b]) + bias, 0.f);
            p1g[((size_t)g * 128 + ct + b) * 50 + jbase]     = m0;
            p1g[((size_t)g * 128 + ct + b) * 50 + jbase + 1] = m1;
        }
    }
}

__global__ void k_w2t(const float* __restrict__ cw2f, float* __restrict__ w2t) {
    int i = blockIdx.x * 256 + threadIdx.x;
    if (i < 64 * 128 * 5) {
        int o = i / 640, r = i % 640, c = r / 5, q = r % 5;
        w2t[(c * 5 + q) * 64 + o] = cw2f[i];
    }
}

// ---------------- conv2 + fc1 + fc3 + log_softmax (1024 threads) ----------------
__global__ __launch_bounds__(1024) void
k_conv2fc(const float* __restrict__ p1g, const float* __restrict__ w2t,
          const float* __restrict__ cb2f,
          const float* __restrict__ fw1t, const float* __restrict__ fb1f,
          const float* __restrict__ fw3f, const float* __restrict__ fb3f,
          const int* __restrict__ flag, void* __restrict__ outp) {
    __shared__ __align__(16) float p1s[128 * 52];   // padded rows for aligned float4 windows
    __shared__ float flat[64 * 46];
    __shared__ float hpart[1024];
    __shared__ float hsh[128];
    int g = blockIdx.x, t = threadIdx.x;
    for (int i = t; i < 128 * 50; i += 1024) {
        int c = i / 50, p = i % 50;
        p1s[c * 52 + p] = p1g[(size_t)g * 6400 + i];
    }
    for (int i = t; i < 128 * 2; i += 1024) {       // zero pad cols 50,51
        int c = i >> 1;
        p1s[c * 52 + 50 + (i & 1)] = 0.f;
    }
    for (int i = t; i < 2944; i += 1024) flat[i] = 0.f;
    __syncthreads();
    {   // conv2: o = lane; (ph, c-eighth) over 16 segments; in-register sliding window
        int o = t & 63;
        int seg = t >> 6;                // 0..15
        int ph = seg & 1, c8 = seg >> 1; // c8: 0..7
        int p0 = ph ? 24 : 0;
        int np = ph ? 22 : 24;
        float acc[24];
        #pragma unroll
        for (int p = 0; p < 24; p++) acc[p] = 0.f;
        int cbeg = c8 * 16;
        for (int c = cbeg; c < cbeg + 16; c++) {
            float win[28];
            const float4* wsrc = (const float4*)&p1s[c * 52 + p0];
            #pragma unroll
            for (int v = 0; v < 7; v++) {
                float4 f = wsrc[v];
                win[4 * v] = f.x; win[4 * v + 1] = f.y; win[4 * v + 2] = f.z; win[4 * v + 3] = f.w;
            }
            #pragma unroll
            for (int q = 0; q < 5; q++) {
                float wv = w2t[(c * 5 + q) * 64 + o];
                #pragma unroll
                for (int p = 0; p < 24; p++) acc[p] += win[p + q] * wv;
            }
        }
        for (int p = 0; p < np; p++) atomicAdd(&flat[o * 46 + p0 + p], acc[p]);
    }
    __syncthreads();
    for (int i = t; i < 2944; i += 1024) {
        int o = i / 46;
        flat[i] = fmaxf(flat[i] + cb2f[o], 0.f);
    }
    __syncthreads();
    {   // fc1: gg = t&127 output, slice = t>>7 covers 368 d's; fw1t coalesced over gg
        int gg = t & 127, slice = t >> 7;
        const float* fl = flat + slice * 368;
        const float* wp = fw1t + (size_t)slice * 368 * 128 + gg;
        float a = 0.f;
        #pragma unroll 4
        for (int d = 0; d < 368; d++) a += fl[d] * wp[(size_t)d * 128];
        hpart[t] = a;
    }
    __syncthreads();
    if (t < 128) {
        float s = fb1f[t];
        #pragma unroll
        for (int s2 = 0; s2 < 8; s2++) s += hpart[t + 128 * s2];
        hsh[t] = fmaxf(s, 0.f);
    }
    __syncthreads();
    if (t == 0) {
        float l0 = fb3f[0], l1 = fb3f[1];
        for (int j = 0; j < 128; j++) {
            l0 += hsh[j] * fw3f[j];
            l1 += hsh[j] * fw3f[128 + j];
        }
        float m = fmaxf(l0, l1);
        float lse = m + logf(expf(l0 - m) + expf(l1 - m));
        if (flag[0]) {
            unsigned short* ob = (unsigned short*)outp;
            ob[g * 2 + 0] = f2bf(l0 - lse);
            ob[g * 2 + 1] = f2bf(l1 - lse);
        } else {
            float* of = (float*)outp;
            of[g * 2 + 0] = l0 - lse;
            of[g * 2 + 1] = l1 - lse;
        }
    }
}

// ---------------- launch ----------------

extern "C" void kernel_launch(void* const* d_in, const int* in_sizes, int n_in,
                              void* d_out, int out_size, void* d_ws, size_t ws_size,
                              hipStream_t stream) {
    const void* x  = d_in[0];
    const int* ei  = (const int*)d_in[1];
    // d_in[2] = batch (arange/400, unused)

    char* p = (char*)d_ws;
    auto alloc = [&](size_t bytes) -> void* {
        void* r = (void*)p;
        p += (bytes + 255) & ~(size_t)255;
        return r;
    };
    int*      flag    = (int*)alloc(256);
    float*    wcv     = (float*)alloc((size_t)OW_TOT * 4);
    float*    fw1t    = (float*)alloc((size_t)376832 * 4);
    int*      ghist   = (int*)alloc((size_t)NBUCK * NCHUNK * 4);
    int*      bcnt    = (int*)alloc(1024 * 4);
    int*      boff    = (int*)alloc(1024 * 4);
    int*      bsums   = (int*)alloc(512 * 4);
    int*      degi    = (int*)alloc((size_t)NNODES * 4);
    int*      row_off = (int*)alloc((size_t)NNODES * 4);
    float*    dis     = (float*)alloc((size_t)NNODES * 4);
    float*    dinv    = (float*)alloc((size_t)NNODES * 4);
    unsigned* staged  = (unsigned*)alloc((size_t)NEDGES * 4);
    int*      csr_src = (int*)alloc((size_t)NPADE * 4);
    float*    csr_cf  = (float*)alloc((size_t)NPADE * 4);
    float*    hbuf    = (float*)alloc((size_t)NNODES * DIM * 4);
    float*    h4buf   = (float*)alloc((size_t)NNODES * 4);
    float*    x1      = (float*)alloc((size_t)NNODES * DIM * 4);
    float*    x2      = (float*)alloc((size_t)NNODES * DIM * 4);
    float*    x3      = (float*)alloc((size_t)NNODES * DIM * 4);
    float*    x4      = (float*)alloc((size_t)NNODES * 4);
    int*      sel     = (int*)alloc((size_t)NGRAPH * KTOP * 4);
    float*    p1g     = (float*)alloc((size_t)NGRAPH * 128 * 50 * 4);
    float*    w2t     = (float*)alloc((size_t)64 * 128 * 5 * 4);
    (void)in_sizes; (void)n_in; (void)out_size; (void)ws_size;

    k_detect<<<1, 256, 0, stream>>>((const unsigned int*)x, flag);
    Srcs sr;
    for (int i = 0; i < 16; i++) sr.p[i] = d_in[3 + i];
    k_convert<<<(OW_TOT + 255) / 256, 256, 0, stream>>>(sr, wcv, flag);
    k_w1t    <<<1472, 256, 0, stream>>>(wcv + OW_FW1, fw1t);

    k_hist     <<<NCHUNK, 256, 0, stream>>>(ei, ghist);
    k_scanChunk<<<NBUCK, 1024, 0, stream>>>(ghist, bcnt);
    k_scanB    <<<1, 1024, 0, stream>>>(bcnt, boff);
    k_binwrite <<<NCHUNK, 256, 0, stream>>>(ei, boff, ghist, staged);
    k_nodecnt  <<<NBUCK, 256, 0, stream>>>(staged, boff, degi);
    k_nodeprep <<<391, 256, 0, stream>>>(degi, dis, dinv);
    k_bsum     <<<391, 256, 0, stream>>>(degi, bsums);
    k_scanb    <<<1, 512, 0, stream>>>(bsums, 391);
    k_scanf    <<<391, 256, 0, stream>>>(degi, bsums, row_off);
    k_csrfix   <<<NBUCK, 256, 0, stream>>>(staged, boff, row_off, dis, csr_src, csr_cf);

    k_mm1   <<<12500, 256, 0, stream>>>(x, wcv + OW_W1, flag, hbuf);
    k_gather<<<12500, 256, 0, stream>>>(hbuf, nullptr, csr_src, csr_cf, row_off, degi, dinv,
                                        wcv + OW_B1, nullptr, x1, nullptr);
    k_mm32  <<<12500, 256, 0, stream>>>(x1, wcv + OW_W2, nullptr, hbuf, nullptr);
    k_gather<<<12500, 256, 0, stream>>>(hbuf, nullptr, csr_src, csr_cf, row_off, degi, dinv,
                                        wcv + OW_B2, nullptr, x2, nullptr);
    k_mm32  <<<12500, 256, 0, stream>>>(x2, wcv + OW_W3, wcv + OW_W4, hbuf, h4buf);
    k_gather<<<12500, 256, 0, stream>>>(hbuf, h4buf, csr_src, csr_cf, row_off, degi, dinv,
                                        wcv + OW_B3, wcv + OW_B4, x3, x4);

    k_sortpool <<<NGRAPH, 256, 0, stream>>>(x4, sel);
    k_conv1pool<<<NGRAPH, 256, 0, stream>>>(x1, x2, x3, x4, sel, wcv + OW_CW1, wcv + OW_CB1, p1g);
    k_w2t      <<<160, 256, 0, stream>>>(wcv + OW_CW2, w2t);
    k_conv2fc  <<<NGRAPH, 1024, 0, stream>>>(p1g, w2t, wcv + OW_CB2, fw1t, wcv + OW_FB1,
                                             wcv + OW_FW3, wcv + OW_FB3, flag, d_out);
}

// Round 8
// 677.200 us; speedup vs baseline: 1.7147x; 1.0325x over previous
//
#include <hip/hip_runtime.h>
#include <hip/hip_bf16.h>

#define NNODES 100000
#define NEDGES 3200000
#define NPADE  4000000  // NEDGES + 8*NNODES worst-case row padding
#define NPER   400
#define NGRAPH 250
#define KTOP   100
#define DIM    32
#define INDIM  128
#define TOTALC 97
#define BSHIFT 7
#define BNODES 128
#define NBUCK  782   // ceil(100000/128)
#define NCHUNK 1024
#define CHSZ   3125  // NEDGES / NCHUNK

__device__ __forceinline__ float bf(unsigned short u) {
    return __uint_as_float(((unsigned)u) << 16);
}
__device__ __forceinline__ unsigned short f2bf(float f) {
    unsigned u = __float_as_uint(f);
    unsigned r = ((u >> 16) & 1u) + 0x7FFFu;   // round-to-nearest-even
    return (unsigned short)((u + r) >> 16);
}

// converted-weights fp32 layout in ws (element offsets, padded to 8)
#define OW_W1   0
#define OW_B1   4096
#define OW_W2   4128
#define OW_B2   5152
#define OW_W3   5184
#define OW_B3   6208
#define OW_W4   6240
#define OW_B4   6272
#define OW_CW1  6280
#define OW_CB1  18696
#define OW_CW2  18824
#define OW_CB2  59784
#define OW_FW1  59848
#define OW_FB1  436680
#define OW_FW3  436808
#define OW_FB3  437064
#define OW_TOT  437072

// ---------------- dtype detect + weight convert ----------------

__global__ void k_detect(const unsigned int* __restrict__ xw, int* __restrict__ flag) {
    __shared__ int cnt[256];
    int t = threadIdx.x, c = 0;
    for (int i = t; i < 4096; i += 256) {
        unsigned e = (xw[i] >> 23) & 0xFFu;
        if (e >= 100u && e <= 150u) c++;
    }
    cnt[t] = c;
    __syncthreads();
    for (int off = 128; off > 0; off >>= 1) {
        if (t < off) cnt[t] += cnt[t + off];
        __syncthreads();
    }
    if (t == 0) flag[0] = (cnt[0] < 2048) ? 1 : 0;   // 1 = inputs are bf16
}

struct Srcs { const void* p[16]; };

__global__ void k_convert(Srcs sr, float* __restrict__ dst, const int* __restrict__ flag) {
    const int st[16] = {OW_W1, OW_B1, OW_W2, OW_B2, OW_W3, OW_B3, OW_W4, OW_B4,
                        OW_CW1, OW_CB1, OW_CW2, OW_CB2, OW_FW1, OW_FB1, OW_FW3, OW_FB3};
    const int nn[16] = {4096, 32, 1024, 32, 1024, 32, 32, 1,
                        12416, 128, 40960, 64, 376832, 128, 256, 2};
    int idx = blockIdx.x * 256 + threadIdx.x;
    if (idx >= OW_TOT) return;
    int isb = flag[0];
    #pragma unroll
    for (int s = 0; s < 16; s++) {
        if (idx >= st[s] && idx < st[s] + nn[s]) {
            int l = idx - st[s];
            dst[idx] = isb ? bf(((const unsigned short*)sr.p[s])[l])
                           : ((const float*)sr.p[s])[l];
        }
    }
}

// fw1 [128][2944] -> fw1t [2944][128] (one-time, L2-resident)
__global__ void k_w1t(const float* __restrict__ fw1f, float* __restrict__ fw1t) {
    int i = blockIdx.x * 256 + threadIdx.x;
    if (i < 376832) {
        int j = i / 2944, d = i % 2944;
        fw1t[d * 128 + j] = fw1f[i];
    }
}

// ---------------- graph prep: contention-free counting sort ----------------

__global__ __launch_bounds__(256) void k_hist(const int* __restrict__ ei, int* __restrict__ ghist) {
    __shared__ int h[NBUCK];
    int c = blockIdx.x, t = threadIdx.x;
    for (int i = t; i < NBUCK; i += 256) h[i] = 0;
    __syncthreads();
    int base = c * CHSZ;
    for (int e = base + t; e < base + CHSZ; e += 256)
        atomicAdd(&h[ei[NEDGES + e] >> BSHIFT], 1);
    __syncthreads();
    for (int i = t; i < NBUCK; i += 256) ghist[i * NCHUNK + c] = h[i];
}

__global__ __launch_bounds__(1024) void k_scanChunk(int* __restrict__ ghist, int* __restrict__ bcnt) {
    __shared__ int s[NCHUNK];
    int b = blockIdx.x, t = threadIdx.x;
    int v = ghist[b * NCHUNK + t];
    s[t] = v;
    __syncthreads();
    for (int o = 1; o < NCHUNK; o <<= 1) {
        int u = (t >= o) ? s[t - o] : 0;
        __syncthreads();
        s[t] += u;
        __syncthreads();
    }
    ghist[b * NCHUNK + t] = s[t] - v;   // exclusive within bucket
    if (t == NCHUNK - 1) bcnt[b] = s[t];
}

__global__ void k_scanB(const int* __restrict__ bcnt, int* __restrict__ boff) {
    __shared__ int s[1024];
    int t = threadIdx.x;
    int v = (t < NBUCK) ? bcnt[t] : 0;
    s[t] = v;
    __syncthreads();
    for (int o = 1; o < 1024; o <<= 1) {
        int u = (t >= o) ? s[t - o] : 0;
        __syncthreads();
        s[t] += u;
        __syncthreads();
    }
    if (t < NBUCK) boff[t] = s[t] - v;   // exclusive
}

__global__ __launch_bounds__(256) void k_binwrite(const int* __restrict__ ei, const int* __restrict__ boff,
                           const int* __restrict__ ghist, unsigned* __restrict__ staged) {
    __shared__ int cur[NBUCK];
    int c = blockIdx.x, t = threadIdx.x;
    for (int i = t; i < NBUCK; i += 256) cur[i] = boff[i] + ghist[i * NCHUNK + c];
    __syncthreads();
    int base = c * CHSZ;
    for (int e = base + t; e < base + CHSZ; e += 256) {
        int s = ei[e], d = ei[NEDGES + e];
        int b = d >> BSHIFT;
        int pos = atomicAdd(&cur[b], 1);
        staged[pos] = ((unsigned)(d & (BNODES - 1)) << 17) | (unsigned)s;
    }
}

__global__ __launch_bounds__(256) void k_nodecnt(const unsigned* __restrict__ staged,
                          const int* __restrict__ boff, int* __restrict__ degi) {
    __shared__ int cnt[BNODES];
    int b = blockIdx.x, t = threadIdx.x;
    if (t < BNODES) cnt[t] = 0;
    __syncthreads();
    int s0 = boff[b];
    int s1 = (b + 1 < NBUCK) ? boff[b + 1] : NEDGES;
    for (int i = s0 + t; i < s1; i += 256)
        atomicAdd(&cnt[staged[i] >> 17], 1);
    __syncthreads();
    int n0 = b << BSHIFT;
    int nn = min(BNODES, NNODES - n0);
    if (t < nn) degi[n0 + t] = cnt[t];
}

__global__ void k_nodeprep(const int* __restrict__ degi, float* __restrict__ dis,
                           float* __restrict__ dinv) {
    int i = blockIdx.x * 256 + threadIdx.x;
    if (i < NNODES) {
        float d = (float)(degi[i] + 1);
        dis[i]  = rsqrtf(d);
        dinv[i] = 1.0f / d;
    }
}

// scans below use PADDED degree (rounded up to 8) so CSR rows are 32B-aligned
__global__ void k_bsum(const int* __restrict__ degi, int* __restrict__ bsums) {
    __shared__ int s[256];
    int t = threadIdx.x;
    int i = blockIdx.x * 256 + t;
    s[t] = (i < NNODES) ? ((degi[i] + 7) & ~7) : 0;
    __syncthreads();
    for (int off = 128; off > 0; off >>= 1) {
        if (t < off) s[t] += s[t + off];
        __syncthreads();
    }
    if (t == 0) bsums[blockIdx.x] = s[0];
}

__global__ void k_scanb(int* __restrict__ bsums, int nb) {
    __shared__ int s[512];
    int t = threadIdx.x;
    int v = (t < nb) ? bsums[t] : 0;
    s[t] = v;
    __syncthreads();
    for (int off = 1; off < 512; off <<= 1) {
        int u = (t >= off) ? s[t - off] : 0;
        __syncthreads();
        s[t] += u;
        __syncthreads();
    }
    if (t < nb) bsums[t] = s[t] - v;   // exclusive
}

__global__ void k_scanf(const int* __restrict__ degi, const int* __restrict__ bsums,
                        int* __restrict__ row_off) {
    __shared__ int s[256];
    int t = threadIdx.x;
    int i = blockIdx.x * 256 + t;
    int v = (i < NNODES) ? ((degi[i] + 7) & ~7) : 0;
    s[t] = v;
    __syncthreads();
    for (int off = 1; off < 256; off <<= 1) {
        int u = (t >= off) ? s[t - off] : 0;
        __syncthreads();
        s[t] += u;
        __syncthreads();
    }
    if (i < NNODES) row_off[i] = bsums[blockIdx.x] + s[t] - v;  // exclusive
}

__global__ __launch_bounds__(256) void k_csrfix(const unsigned* __restrict__ staged,
                         const int* __restrict__ boff, const int* __restrict__ row_off,
                         const float* __restrict__ dis,
                         int* __restrict__ csr_src, float* __restrict__ csr_cf) {
    __shared__ int cnt[BNODES];
    __shared__ int rofs[BNODES];
    __shared__ float disl[BNODES];
    int b = blockIdx.x, t = threadIdx.x;
    int n0 = b << BSHIFT;
    int nn = min(BNODES, NNODES - n0);
    if (t < BNODES) {
        cnt[t]  = 0;
        rofs[t] = (t < nn) ? row_off[n0 + t] : 0;
        disl[t] = (t < nn) ? dis[n0 + t] : 0.f;
    }
    __syncthreads();
    int s0 = boff[b];
    int s1 = (b + 1 < NBUCK) ? boff[b + 1] : NEDGES;
    for (int i = s0 + t; i < s1; i += 256) {
        unsigned rec = staged[i];
        int dl = rec >> 17, s = rec & 0x1FFFF;
        int r = atomicAdd(&cnt[dl], 1);
        int slot = rofs[dl] + r;
        csr_src[slot] = s;
        csr_cf[slot]  = dis[s] * disl[dl];
    }
    __syncthreads();
    if (t < nn) {   // inert pad entries: src=0 (harmless read), cf=0
        int d = cnt[t], dp = (d + 7) & ~7;
        for (int s2 = d; s2 < dp; s2++) {
            csr_src[rofs[t] + s2] = 0;
            csr_cf[rofs[t] + s2]  = 0.f;
        }
    }
}

// ---------------- GCN dense parts ----------------

__global__ void k_mm1(const void* __restrict__ xraw, const float* __restrict__ W1f,
                      const int* __restrict__ flag, float* __restrict__ h) {
    __shared__ float w[INDIM * DIM];
    __shared__ float xsh[8 * INDIM];
    int t = threadIdx.x;
    for (int i = t; i < INDIM * DIM; i += 256) w[i] = W1f[i];
    if (flag[0]) {
        const unsigned int* xsrc = (const unsigned int*)((const unsigned short*)xraw
                                   + (size_t)blockIdx.x * 8 * INDIM);
        for (int i = t; i < 512; i += 256) {
            unsigned u = xsrc[i];
            xsh[2 * i]     = __uint_as_float(u << 16);
            xsh[2 * i + 1] = __uint_as_float(u & 0xFFFF0000u);
        }
    } else {
        const float4* xsrc = (const float4*)((const float*)xraw + (size_t)blockIdx.x * 8 * INDIM);
        float4* xdst = (float4*)xsh;
        for (int i = t; i < 256; i += 256) xdst[i] = xsrc[i];
    }
    __syncthreads();
    int ln = t >> 5, c = t & 31;
    const float* xr = xsh + ln * INDIM;
    float acc = 0.f;
    #pragma unroll 8
    for (int j = 0; j < INDIM; j++) acc += xr[j] * w[j * DIM + c];
    h[(size_t)blockIdx.x * 256 + t] = acc;
}

__global__ void k_mm32(const float* __restrict__ xin, const float* __restrict__ W,
                       const float* __restrict__ W4, float* __restrict__ h,
                       float* __restrict__ h4) {
    __shared__ float w[DIM * DIM];
    __shared__ float w4s[DIM];
    __shared__ float xsh[8 * DIM];
    int t = threadIdx.x;
    for (int i = t; i < DIM * DIM; i += 256) w[i] = W[i];
    if (W4 && t < DIM) w4s[t] = W4[t];
    for (int i = t; i < 8 * DIM; i += 256) xsh[i] = xin[(size_t)blockIdx.x * 256 + i];
    __syncthreads();
    int ln = t >> 5, c = t & 31;
    const float* xr = xsh + ln * DIM;
    float acc = 0.f;
    #pragma unroll
    for (int j = 0; j < DIM; j++) acc += xr[j] * w[j * DIM + c];
    h[(size_t)blockIdx.x * 256 + t] = acc;
    if (W4 && c == 0) {
        float a4 = 0.f;
        #pragma unroll
        for (int j = 0; j < DIM; j++) a4 += xr[j] * w4s[j];
        h4[blockIdx.x * 8 + ln] = a4;
    }
}

// per node: 32 lanes = channels; 8-wide CSR (two quads) with named-register
// prefetch — NO dynamically-indexed locals (R6: those lower to LDS scratch).
__global__ void k_gather(const float* __restrict__ h, const float* __restrict__ h4,
                         const int* __restrict__ csr_src, const float* __restrict__ csr_cf,
                         const int* __restrict__ row_off, const int* __restrict__ degi,
                         const float* __restrict__ dinv, const float* __restrict__ bias,
                         const float* __restrict__ b4,
                         float* __restrict__ xout, float* __restrict__ x4out) {
    int t = threadIdx.x;
    int node = blockIdx.x * 8 + (t >> 5);
    int lane = t & 31;
    int start = row_off[node];           // multiple of 8 -> 32B aligned
    int cnt   = degi[node];
    int iters = (cnt + 7) >> 3;          // pairs of quads
    const int4*   ip = (const int4*)(csr_src + start);
    const float4* cp = (const float4*)(csr_cf + start);
    float acc0 = 0.f, acc1 = 0.f;
    if (iters > 0) {
        int4   iA = ip[0], iB = ip[1];
        float4 cA = cp[0], cB = cp[1];
        for (int k = 1; k < iters; k++) {
            int4   nA = ip[2 * k],     nB = ip[2 * k + 1];
            float4 dA = cp[2 * k],     dB = cp[2 * k + 1];
            acc0 += h[(size_t)iA.x * DIM + lane] * cA.x;
            acc1 += h[(size_t)iA.y * DIM + lane] * cA.y;
            acc0 += h[(size_t)iA.z * DIM + lane] * cA.z;
            acc1 += h[(size_t)iA.w * DIM + lane] * cA.w;
            acc0 += h[(size_t)iB.x * DIM + lane] * cB.x;
            acc1 += h[(size_t)iB.y * DIM + lane] * cB.y;
            acc0 += h[(size_t)iB.z * DIM + lane] * cB.z;
            acc1 += h[(size_t)iB.w * DIM + lane] * cB.w;
            iA = nA; iB = nB; cA = dA; cB = dB;
        }
        acc0 += h[(size_t)iA.x * DIM + lane] * cA.x;
        acc1 += h[(size_t)iA.y * DIM + lane] * cA.y;
        acc0 += h[(size_t)iA.z * DIM + lane] * cA.z;
        acc1 += h[(size_t)iA.w * DIM + lane] * cA.w;
        acc0 += h[(size_t)iB.x * DIM + lane] * cB.x;
        acc1 += h[(size_t)iB.y * DIM + lane] * cB.y;
        acc0 += h[(size_t)iB.z * DIM + lane] * cB.z;
        acc1 += h[(size_t)iB.w * DIM + lane] * cB.w;
    }
    float di = dinv[node];
    float outv = tanhf(acc0 + acc1 + h[(size_t)node * DIM + lane] * di + bias[lane]);
    xout[(size_t)node * DIM + lane] = outv;
    if (h4) {
        int cntp = iters << 3;
        float a4 = 0.f;
        for (int ee = lane; ee < cntp; ee += 32)
            a4 += h4[csr_src[start + ee]] * csr_cf[start + ee];
        for (int off = 16; off > 0; off >>= 1) a4 += __shfl_xor(a4, off, 32);
        if (lane == 0) x4out[node] = tanhf(a4 + h4[node] * di + b4[0]);
    }
}

// ---------------- sort pooling ----------------
__global__ void k_sortpool(const float* __restrict__ x4, int* __restrict__ sel) {
    __shared__ unsigned long long keys[512];
    int g = blockIdx.x, t = threadIdx.x;
    for (int i = t; i < 512; i += 256) {
        unsigned long long kk = 0xFFFFFFFFFFFFFFFFULL;
        if (i < NPER) {
            unsigned u = __float_as_uint(x4[g * NPER + i]);
            u = (u & 0x80000000u) ? ~u : (u | 0x80000000u);
            kk = ((unsigned long long)(~u) << 32) | (unsigned)i;
        }
        keys[i] = kk;
    }
    __syncthreads();
    for (int k = 2; k <= 512; k <<= 1)
        for (int j = k >> 1; j > 0; j >>= 1) {
            for (int i = t; i < 512; i += 256) {
                int l = i ^ j;
                if (l > i) {
                    unsigned long long a = keys[i], b = keys[l];
                    bool asc = ((i & k) == 0);
                    if ((a > b) == asc) { keys[i] = b; keys[l] = a; }
                }
            }
            __syncthreads();
        }
    for (int i = t; i < KTOP; i += 256)
        sel[g * KTOP + i] = g * NPER + (int)(unsigned)(keys[i] & 0xFFFFFFFFu);
}

// ---------------- conv1 (per-slot linear) + maxpool ----------------
__global__ void k_conv1pool(const float* __restrict__ x1, const float* __restrict__ x2,
                            const float* __restrict__ x3, const float* __restrict__ x4,
                            const int* __restrict__ sel, const float* __restrict__ cw1f,
                            const float* __restrict__ cb1f, float* __restrict__ p1g) {
    __shared__ __align__(16) float xs[32 * 100];   // [q][k]
    __shared__ __align__(16) float ws[32 * 128];   // [q][c]
    __shared__ int nsh[KTOP];
    int g = blockIdx.x, t = threadIdx.x;
    if (t < KTOP) nsh[t] = sel[g * KTOP + t];
    int ct = (t & 31) * 4;
    int kbase = (t >> 5) * 4;           // kt for set s = kbase + 32*s
    int nset = (t < 32) ? 4 : 3;        // tiles t+256*s, valid while < 800
    float acc[4][4][4] = {};            // [set][k-off][c-off]
    for (int ch = 0; ch < 3; ch++) {
        const float* arr = (ch == 0) ? x1 : (ch == 1) ? x2 : x3;
        __syncthreads();
        for (int i = t; i < 3200; i += 256) {       // q fastest → coalesced node rows
            int q = i & 31, k = i >> 5;
            xs[q * 100 + k] = arr[(size_t)nsh[k] * 32 + q];
        }
        for (int i = t; i < 4096; i += 256) {       // c fastest → conflict-free LDS write
            int c = i & 127, q = i >> 7;
            ws[q * 128 + c] = cw1f[c * TOTALC + ch * 32 + q];
        }
        __syncthreads();
        for (int q = 0; q < 32; q++) {
            float4 wv = *(const float4*)&ws[q * 128 + ct];
            #pragma unroll
            for (int s = 0; s < 4; s++) {
                if (s >= nset) break;
                float4 xv = *(const float4*)&xs[q * 100 + kbase + 32 * s];
                float xa[4] = { xv.x, xv.y, xv.z, xv.w };
                float wa[4] = { wv.x, wv.y, wv.z, wv.w };
                #pragma unroll
                for (int a = 0; a < 4; a++)
                    #pragma unroll
                    for (int b = 0; b < 4; b++)
                        acc[s][a][b] += xa[a] * wa[b];
            }
        }
    }
    {   // tail channel q = 96 (x4)
        float wa[4];
        #pragma unroll
        for (int b = 0; b < 4; b++) wa[b] = cw1f[(ct + b) * TOTALC + 96];
        for (int s = 0; s < nset; s++) {
            int kt = kbase + 32 * s;
            #pragma unroll
            for (int a = 0; a < 4; a++) {
                float xv = x4[nsh[kt + a]];
                #pragma unroll
                for (int b = 0; b < 4; b++) acc[s][a][b] += xv * wa[b];
            }
        }
    }
    for (int s = 0; s < nset; s++) {
        int kt = kbase + 32 * s;
        int jbase = kt >> 1;
        #pragma unroll
        for (int b = 0; b < 4; b++) {
            float bias = cb1f[ct + b];
            float m0 = fmaxf(fmaxf(acc[s][0][b], acc[s][1][b]) + bias, 0.f);
            float m1 = fmaxf(fmaxf(acc[s][2][b], acc[s][3][b]) + bias, 0.f);
            p1g[((size_t)g * 128 + ct + b) * 50 + jbase]     = m0;
            p1g[((size_t)g * 128 + ct + b) * 50 + jbase + 1] = m1;
        }
    }
}

__global__ void k_w2t(const float* __restrict__ cw2f, float* __restrict__ w2t) {
    int i = blockIdx.x * 256 + threadIdx.x;
    if (i < 64 * 128 * 5) {
        int o = i / 640, r = i % 640, c = r / 5, q = r % 5;
        w2t[(c * 5 + q) * 64 + o] = cw2f[i];
    }
}

// ---------------- conv2 + fc1 + fc3 + log_softmax (1024 threads) ----------------
__global__ __launch_bounds__(1024) void
k_conv2fc(const float* __restrict__ p1g, const float* __restrict__ w2t,
          const float* __restrict__ cb2f,
          const float* __restrict__ fw1t, const float* __restrict__ fb1f,
          const float* __restrict__ fw3f, const float* __restrict__ fb3f,
          const int* __restrict__ flag, void* __restrict__ outp) {
    __shared__ __align__(16) float p1s[128 * 52];   // padded rows for aligned float4 windows
    __shared__ float flat[64 * 46];
    __shared__ float hpart[1024];
    __shared__ float hsh[128];
    int g = blockIdx.x, t = threadIdx.x;
    for (int i = t; i < 128 * 50; i += 1024) {
        int c = i / 50, p = i % 50;
        p1s[c * 52 + p] = p1g[(size_t)g * 6400 + i];
    }
    for (int i = t; i < 128 * 2; i += 1024) {       // zero pad cols 50,51
        int c = i >> 1;
        p1s[c * 52 + 50 + (i & 1)] = 0.f;
    }
    for (int i = t; i < 2944; i += 1024) flat[i] = 0.f;
    __syncthreads();
    {   // conv2: o = lane; (ph, c-eighth) over 16 segments; all 5 w-loads hoisted
        int o = t & 63;
        int seg = t >> 6;                // 0..15
        int ph = seg & 1, c8 = seg >> 1; // c8: 0..7
        int p0 = ph ? 24 : 0;
        int np = ph ? 22 : 24;
        float acc[24];
        #pragma unroll
        for (int p = 0; p < 24; p++) acc[p] = 0.f;
        int cbeg = c8 * 16;
        for (int c = cbeg; c < cbeg + 16; c++) {
            const float* wb = w2t + c * 320 + o;    // (c*5+q)*64+o
            float w0 = wb[0], w1 = wb[64], w2 = wb[128], w3 = wb[192], w4 = wb[256];
            float win[28];
            const float4* wsrc = (const float4*)&p1s[c * 52 + p0];
            #pragma unroll
            for (int v = 0; v < 7; v++) {
                float4 f = wsrc[v];
                win[4 * v] = f.x; win[4 * v + 1] = f.y; win[4 * v + 2] = f.z; win[4 * v + 3] = f.w;
            }
            #pragma unroll
            for (int p = 0; p < 24; p++)
                acc[p] += win[p] * w0 + win[p + 1] * w1 + win[p + 2] * w2
                        + win[p + 3] * w3 + win[p + 4] * w4;
        }
        for (int p = 0; p < np; p++) atomicAdd(&flat[o * 46 + p0 + p], acc[p]);
    }
    __syncthreads();
    for (int i = t; i < 2944; i += 1024) {
        int o = i / 46;
        flat[i] = fmaxf(flat[i] + cb2f[o], 0.f);
    }
    __syncthreads();
    {   // fc1: gg = t&127 output, slice = t>>7 covers 368 d's; fw1t coalesced over gg
        int gg = t & 127, slice = t >> 7;
        const float* fl = flat + slice * 368;
        const float* wp = fw1t + (size_t)slice * 368 * 128 + gg;
        float a = 0.f;
        #pragma unroll 8
        for (int d = 0; d < 368; d++) a += fl[d] * wp[(size_t)d * 128];
        hpart[t] = a;
    }
    __syncthreads();
    if (t < 128) {
        float s = fb1f[t];
        #pragma unroll
        for (int s2 = 0; s2 < 8; s2++) s += hpart[t + 128 * s2];
        hsh[t] = fmaxf(s, 0.f);
    }
    __syncthreads();
    if (t < 64) {   // fc3 + log_softmax: 64-lane parallel reduce
        float h0 = hsh[t], h1 = hsh[t + 64];
        float l0 = h0 * fw3f[t] + h1 * fw3f[t + 64];
        float l1 = h0 * fw3f[128 + t] + h1 * fw3f[192 + t];
        #pragma unroll
        for (int off = 32; off > 0; off >>= 1) {
            l0 += __shfl_down(l0, off, 64);
            l1 += __shfl_down(l1, off, 64);
        }
        if (t == 0) {
            l0 += fb3f[0]; l1 += fb3f[1];
            float m = fmaxf(l0, l1);
            float lse = m + logf(expf(l0 - m) + expf(l1 - m));
            if (flag[0]) {
                unsigned short* ob = (unsigned short*)outp;
                ob[g * 2 + 0] = f2bf(l0 - lse);
                ob[g * 2 + 1] = f2bf(l1 - lse);
            } else {
                float* of = (float*)outp;
                of[g * 2 + 0] = l0 - lse;
                of[g * 2 + 1] = l1 - lse;
            }
        }
    }
}

// ---------------- launch ----------------

extern "C" void kernel_launch(void* const* d_in, const int* in_sizes, int n_in,
                              void* d_out, int out_size, void* d_ws, size_t ws_size,
                              hipStream_t stream) {
    const void* x  = d_in[0];
    const int* ei  = (const int*)d_in[1];
    // d_in[2] = batch (arange/400, unused)

    char* p = (char*)d_ws;
    auto alloc = [&](size_t bytes) -> void* {
        void* r = (void*)p;
        p += (bytes + 255) & ~(size_t)255;
        return r;
    };
    int*      flag    = (int*)alloc(256);
    float*    wcv     = (float*)alloc((size_t)OW_TOT * 4);
    float*    fw1t    = (float*)alloc((size_t)376832 * 4);
    int*      ghist   = (int*)alloc((size_t)NBUCK * NCHUNK * 4);
    int*      bcnt    = (int*)alloc(1024 * 4);
    int*      boff    = (int*)alloc(1024 * 4);
    int*      bsums   = (int*)alloc(512 * 4);
    int*      degi    = (int*)alloc((size_t)NNODES * 4);
    int*      row_off = (int*)alloc((size_t)NNODES * 4);
    float*    dis     = (float*)alloc((size_t)NNODES * 4);
    float*    dinv    = (float*)alloc((size_t)NNODES * 4);
    unsigned* staged  = (unsigned*)alloc((size_t)NEDGES * 4);
    int*      csr_src = (int*)alloc((size_t)NPADE * 4);
    float*    csr_cf  = (float*)alloc((size_t)NPADE * 4);
    float*    hbuf    = (float*)alloc((size_t)NNODES * DIM * 4);
    float*    h4buf   = (float*)alloc((size_t)NNODES * 4);
    float*    x1      = (float*)alloc((size_t)NNODES * DIM * 4);
    float*    x2      = (float*)alloc((size_t)NNODES * DIM * 4);
    float*    x3      = (float*)alloc((size_t)NNODES * DIM * 4);
    float*    x4      = (float*)alloc((size_t)NNODES * 4);
    int*      sel     = (int*)alloc((size_t)NGRAPH * KTOP * 4);
    float*    p1g     = (float*)alloc((size_t)NGRAPH * 128 * 50 * 4);
    float*    w2t     = (float*)alloc((size_t)64 * 128 * 5 * 4);
    (void)in_sizes; (void)n_in; (void)out_size; (void)ws_size;

    k_detect<<<1, 256, 0, stream>>>((const unsigned int*)x, flag);
    Srcs sr;
    for (int i = 0; i < 16; i++) sr.p[i] = d_in[3 + i];
    k_convert<<<(OW_TOT + 255) / 256, 256, 0, stream>>>(sr, wcv, flag);
    k_w1t    <<<1472, 256, 0, stream>>>(wcv + OW_FW1, fw1t);

    k_hist     <<<NCHUNK, 256, 0, stream>>>(ei, ghist);
    k_scanChunk<<<NBUCK, 1024, 0, stream>>>(ghist, bcnt);
    k_scanB    <<<1, 1024, 0, stream>>>(bcnt, boff);
    k_binwrite <<<NCHUNK, 256, 0, stream>>>(ei, boff, ghist, staged);
    k_nodecnt  <<<NBUCK, 256, 0, stream>>>(staged, boff, degi);
    k_nodeprep <<<391, 256, 0, stream>>>(degi, dis, dinv);
    k_bsum     <<<391, 256, 0, stream>>>(degi, bsums);
    k_scanb    <<<1, 512, 0, stream>>>(bsums, 391);
    k_scanf    <<<391, 256, 0, stream>>>(degi, bsums, row_off);
    k_csrfix   <<<NBUCK, 256, 0, stream>>>(staged, boff, row_off, dis, csr_src, csr_cf);

    k_mm1   <<<12500, 256, 0, stream>>>(x, wcv + OW_W1, flag, hbuf);
    k_gather<<<12500, 256, 0, stream>>>(hbuf, nullptr, csr_src, csr_cf, row_off, degi, dinv,
                                        wcv + OW_B1, nullptr, x1, nullptr);
    k_mm32  <<<12500, 256, 0, stream>>>(x1, wcv + OW_W2, nullptr, hbuf, nullptr);
    k_gather<<<12500, 256, 0, stream>>>(hbuf, nullptr, csr_src, csr_cf, row_off, degi, dinv,
                                        wcv + OW_B2, nullptr, x2, nullptr);
    k_mm32  <<<12500, 256, 0, stream>>>(x2, wcv + OW_W3, wcv + OW_W4, hbuf, h4buf);
    k_gather<<<12500, 256, 0, stream>>>(hbuf, h4buf, csr_src, csr_cf, row_off, degi, dinv,
                                        wcv + OW_B3, wcv + OW_B4, x3, x4);

    k_sortpool <<<NGRAPH, 256, 0, stream>>>(x4, sel);
    k_conv1pool<<<NGRAPH, 256, 0, stream>>>(x1, x2, x3, x4, sel, wcv + OW_CW1, wcv + OW_CB1, p1g);
    k_w2t      <<<160, 256, 0, stream>>>(wcv + OW_CW2, w2t);
    k_conv2fc  <<<NGRAPH, 1024, 0, stream>>>(p1g, w2t, wcv + OW_CB2, fw1t, wcv + OW_FB1,
                                             wcv + OW_FW3, wcv + OW_FB3, flag, d_out);
}

// Round 9
// 617.506 us; speedup vs baseline: 1.8804x; 1.0967x over previous
//
#include <hip/hip_runtime.h>
#include <hip/hip_bf16.h>

#define NNODES 100000
#define NEDGES 3200000
#define NPADE  4000000  // NEDGES + 8*NNODES worst-case row padding
#define NPER   400
#define NGRAPH 250
#define KTOP   100
#define DIM    32
#define INDIM  128
#define TOTALC 97
#define BSHIFT 7
#define BNODES 128
#define NBUCK  782   // ceil(100000/128)
#define NCHUNK 200
#define CHSZ   16000 // NEDGES / NCHUNK

__device__ __forceinline__ float bf(unsigned short u) {
    return __uint_as_float(((unsigned)u) << 16);
}
__device__ __forceinline__ unsigned short f2bf(float f) {
    unsigned u = __float_as_uint(f);
    unsigned r = ((u >> 16) & 1u) + 0x7FFFu;   // round-to-nearest-even
    return (unsigned short)((u + r) >> 16);
}

// converted-weights fp32 layout in ws (element offsets, padded to 8)
#define OW_W1   0
#define OW_B1   4096
#define OW_W2   4128
#define OW_B2   5152
#define OW_W3   5184
#define OW_B3   6208
#define OW_W4   6240
#define OW_B4   6272
#define OW_CW1  6280
#define OW_CB1  18696
#define OW_CW2  18824
#define OW_CB2  59784
#define OW_FW1  59848
#define OW_FB1  436680
#define OW_FW3  436808
#define OW_FB3  437064
#define OW_TOT  437072

// ---------------- dtype detect + weight convert ----------------

__global__ void k_detect(const unsigned int* __restrict__ xw, int* __restrict__ flag) {
    __shared__ int cnt[256];
    int t = threadIdx.x, c = 0;
    for (int i = t; i < 4096; i += 256) {
        unsigned e = (xw[i] >> 23) & 0xFFu;
        if (e >= 100u && e <= 150u) c++;
    }
    cnt[t] = c;
    __syncthreads();
    for (int off = 128; off > 0; off >>= 1) {
        if (t < off) cnt[t] += cnt[t + off];
        __syncthreads();
    }
    if (t == 0) flag[0] = (cnt[0] < 2048) ? 1 : 0;   // 1 = inputs are bf16
}

struct Srcs { const void* p[16]; };

__global__ void k_convert(Srcs sr, float* __restrict__ dst, const int* __restrict__ flag) {
    const int st[16] = {OW_W1, OW_B1, OW_W2, OW_B2, OW_W3, OW_B3, OW_W4, OW_B4,
                        OW_CW1, OW_CB1, OW_CW2, OW_CB2, OW_FW1, OW_FB1, OW_FW3, OW_FB3};
    const int nn[16] = {4096, 32, 1024, 32, 1024, 32, 32, 1,
                        12416, 128, 40960, 64, 376832, 128, 256, 2};
    int idx = blockIdx.x * 256 + threadIdx.x;
    if (idx >= OW_TOT) return;
    int isb = flag[0];
    #pragma unroll
    for (int s = 0; s < 16; s++) {
        if (idx >= st[s] && idx < st[s] + nn[s]) {
            int l = idx - st[s];
            dst[idx] = isb ? bf(((const unsigned short*)sr.p[s])[l])
                           : ((const float*)sr.p[s])[l];
        }
    }
}

// fw1 [128][2944] -> fw1t [2944][128] (one-time, L2-resident)
__global__ void k_w1t(const float* __restrict__ fw1f, float* __restrict__ fw1t) {
    int i = blockIdx.x * 256 + threadIdx.x;
    if (i < 376832) {
        int j = i / 2944, d = i % 2944;
        fw1t[d * 128 + j] = fw1f[i];
    }
}

// ---------------- graph prep: contention-free counting sort ----------------
// NCHUNK=200 so each (chunk,bucket) segment ~20 edges = 80B >= one 64B line
// (R8: NCHUNK=1024 gave 16B segments -> 6.7x write amplification in binwrite).

__global__ __launch_bounds__(1024) void k_hist(const int* __restrict__ ei, int* __restrict__ ghist) {
    __shared__ int h[NBUCK];
    int c = blockIdx.x, t = threadIdx.x;
    for (int i = t; i < NBUCK; i += 1024) h[i] = 0;
    __syncthreads();
    int base = c * CHSZ;
    for (int e = base + t; e < base + CHSZ; e += 1024)
        atomicAdd(&h[ei[NEDGES + e] >> BSHIFT], 1);
    __syncthreads();
    for (int i = t; i < NBUCK; i += 1024) ghist[i * NCHUNK + c] = h[i];
}

__global__ __launch_bounds__(256) void k_scanChunk(int* __restrict__ ghist, int* __restrict__ bcnt) {
    __shared__ int s[256];
    int b = blockIdx.x, t = threadIdx.x;
    int v = (t < NCHUNK) ? ghist[b * NCHUNK + t] : 0;
    s[t] = v;
    __syncthreads();
    for (int o = 1; o < 256; o <<= 1) {
        int u = (t >= o) ? s[t - o] : 0;
        __syncthreads();
        s[t] += u;
        __syncthreads();
    }
    if (t < NCHUNK) ghist[b * NCHUNK + t] = s[t] - v;   // exclusive within bucket
    if (t == NCHUNK - 1) bcnt[b] = s[t];
}

__global__ void k_scanB(const int* __restrict__ bcnt, int* __restrict__ boff) {
    __shared__ int s[1024];
    int t = threadIdx.x;
    int v = (t < NBUCK) ? bcnt[t] : 0;
    s[t] = v;
    __syncthreads();
    for (int o = 1; o < 1024; o <<= 1) {
        int u = (t >= o) ? s[t - o] : 0;
        __syncthreads();
        s[t] += u;
        __syncthreads();
    }
    if (t < NBUCK) boff[t] = s[t] - v;   // exclusive
}

__global__ __launch_bounds__(1024) void k_binwrite(const int* __restrict__ ei, const int* __restrict__ boff,
                           const int* __restrict__ ghist, unsigned* __restrict__ staged) {
    __shared__ int cur[NBUCK];
    int c = blockIdx.x, t = threadIdx.x;
    for (int i = t; i < NBUCK; i += 1024) cur[i] = boff[i] + ghist[i * NCHUNK + c];
    __syncthreads();
    int base = c * CHSZ;
    for (int e = base + t; e < base + CHSZ; e += 1024) {
        int s = ei[e], d = ei[NEDGES + e];
        int b = d >> BSHIFT;
        int pos = atomicAdd(&cur[b], 1);
        staged[pos] = ((unsigned)(d & (BNODES - 1)) << 17) | (unsigned)s;
    }
}

__global__ __launch_bounds__(256) void k_nodecnt(const unsigned* __restrict__ staged,
                          const int* __restrict__ boff, int* __restrict__ degi) {
    __shared__ int cnt[BNODES];
    int b = blockIdx.x, t = threadIdx.x;
    if (t < BNODES) cnt[t] = 0;
    __syncthreads();
    int s0 = boff[b];
    int s1 = (b + 1 < NBUCK) ? boff[b + 1] : NEDGES;
    for (int i = s0 + t; i < s1; i += 256)
        atomicAdd(&cnt[staged[i] >> 17], 1);
    __syncthreads();
    int n0 = b << BSHIFT;
    int nn = min(BNODES, NNODES - n0);
    if (t < nn) degi[n0 + t] = cnt[t];
}

__global__ void k_nodeprep(const int* __restrict__ degi, float* __restrict__ dis,
                           float* __restrict__ dinv) {
    int i = blockIdx.x * 256 + threadIdx.x;
    if (i < NNODES) {
        float d = (float)(degi[i] + 1);
        dis[i]  = rsqrtf(d);
        dinv[i] = 1.0f / d;
    }
}

// scans below use PADDED degree (rounded up to 8) so CSR rows are 32B-aligned
__global__ void k_bsum(const int* __restrict__ degi, int* __restrict__ bsums) {
    __shared__ int s[256];
    int t = threadIdx.x;
    int i = blockIdx.x * 256 + t;
    s[t] = (i < NNODES) ? ((degi[i] + 7) & ~7) : 0;
    __syncthreads();
    for (int off = 128; off > 0; off >>= 1) {
        if (t < off) s[t] += s[t + off];
        __syncthreads();
    }
    if (t == 0) bsums[blockIdx.x] = s[0];
}

__global__ void k_scanb(int* __restrict__ bsums, int nb) {
    __shared__ int s[512];
    int t = threadIdx.x;
    int v = (t < nb) ? bsums[t] : 0;
    s[t] = v;
    __syncthreads();
    for (int off = 1; off < 512; off <<= 1) {
        int u = (t >= off) ? s[t - off] : 0;
        __syncthreads();
        s[t] += u;
        __syncthreads();
    }
    if (t < nb) bsums[t] = s[t] - v;   // exclusive
}

__global__ void k_scanf(const int* __restrict__ degi, const int* __restrict__ bsums,
                        int* __restrict__ row_off) {
    __shared__ int s[256];
    int t = threadIdx.x;
    int i = blockIdx.x * 256 + t;
    int v = (i < NNODES) ? ((degi[i] + 7) & ~7) : 0;
    s[t] = v;
    __syncthreads();
    for (int off = 1; off < 256; off <<= 1) {
        int u = (t >= off) ? s[t - off] : 0;
        __syncthreads();
        s[t] += u;
        __syncthreads();
    }
    if (i < NNODES) row_off[i] = bsums[blockIdx.x] + s[t] - v;  // exclusive
}

__global__ __launch_bounds__(256) void k_csrfix(const unsigned* __restrict__ staged,
                         const int* __restrict__ boff, const int* __restrict__ row_off,
                         const float* __restrict__ dis,
                         int* __restrict__ csr_src, float* __restrict__ csr_cf) {
    __shared__ int cnt[BNODES];
    __shared__ int rofs[BNODES];
    __shared__ float disl[BNODES];
    int b = blockIdx.x, t = threadIdx.x;
    int n0 = b << BSHIFT;
    int nn = min(BNODES, NNODES - n0);
    if (t < BNODES) {
        cnt[t]  = 0;
        rofs[t] = (t < nn) ? row_off[n0 + t] : 0;
        disl[t] = (t < nn) ? dis[n0 + t] : 0.f;
    }
    __syncthreads();
    int s0 = boff[b];
    int s1 = (b + 1 < NBUCK) ? boff[b + 1] : NEDGES;
    for (int i = s0 + t; i < s1; i += 256) {
        unsigned rec = staged[i];
        int dl = rec >> 17, s = rec & 0x1FFFF;
        int r = atomicAdd(&cnt[dl], 1);
        int slot = rofs[dl] + r;
        csr_src[slot] = s;
        csr_cf[slot]  = dis[s] * disl[dl];
    }
    __syncthreads();
    if (t < nn) {   // inert pad entries: src=0 (harmless read), cf=0
        int d = cnt[t], dp = (d + 7) & ~7;
        for (int s2 = d; s2 < dp; s2++) {
            csr_src[rofs[t] + s2] = 0;
            csr_cf[rofs[t] + s2]  = 0.f;
        }
    }
}

// ---------------- GCN dense parts ----------------

__global__ void k_mm1(const void* __restrict__ xraw, const float* __restrict__ W1f,
                      const int* __restrict__ flag, float* __restrict__ h) {
    __shared__ float w[INDIM * DIM];
    __shared__ float xsh[8 * INDIM];
    int t = threadIdx.x;
    for (int i = t; i < INDIM * DIM; i += 256) w[i] = W1f[i];
    if (flag[0]) {
        const unsigned int* xsrc = (const unsigned int*)((const unsigned short*)xraw
                                   + (size_t)blockIdx.x * 8 * INDIM);
        for (int i = t; i < 512; i += 256) {
            unsigned u = xsrc[i];
            xsh[2 * i]     = __uint_as_float(u << 16);
            xsh[2 * i + 1] = __uint_as_float(u & 0xFFFF0000u);
        }
    } else {
        const float4* xsrc = (const float4*)((const float*)xraw + (size_t)blockIdx.x * 8 * INDIM);
        float4* xdst = (float4*)xsh;
        for (int i = t; i < 256; i += 256) xdst[i] = xsrc[i];
    }
    __syncthreads();
    int ln = t >> 5, c = t & 31;
    const float* xr = xsh + ln * INDIM;
    float acc = 0.f;
    #pragma unroll 8
    for (int j = 0; j < INDIM; j++) acc += xr[j] * w[j * DIM + c];
    h[(size_t)blockIdx.x * 256 + t] = acc;
}

__global__ void k_mm32(const float* __restrict__ xin, const float* __restrict__ W,
                       const float* __restrict__ W4, float* __restrict__ h,
                       float* __restrict__ h4) {
    __shared__ float w[DIM * DIM];
    __shared__ float w4s[DIM];
    __shared__ float xsh[8 * DIM];
    int t = threadIdx.x;
    for (int i = t; i < DIM * DIM; i += 256) w[i] = W[i];
    if (W4 && t < DIM) w4s[t] = W4[t];
    for (int i = t; i < 8 * DIM; i += 256) xsh[i] = xin[(size_t)blockIdx.x * 256 + i];
    __syncthreads();
    int ln = t >> 5, c = t & 31;
    const float* xr = xsh + ln * DIM;
    float acc = 0.f;
    #pragma unroll
    for (int j = 0; j < DIM; j++) acc += xr[j] * w[j * DIM + c];
    h[(size_t)blockIdx.x * 256 + t] = acc;
    if (W4 && c == 0) {
        float a4 = 0.f;
        #pragma unroll
        for (int j = 0; j < DIM; j++) a4 += xr[j] * w4s[j];
        h4[blockIdx.x * 8 + ln] = a4;
    }
}

// per node: 32 lanes = channels; 8-wide CSR (two quads) with named-register
// prefetch — NO dynamically-indexed locals (R6: those lower to LDS scratch).
__global__ void k_gather(const float* __restrict__ h, const float* __restrict__ h4,
                         const int* __restrict__ csr_src, const float* __restrict__ csr_cf,
                         const int* __restrict__ row_off, const int* __restrict__ degi,
                         const float* __restrict__ dinv, const float* __restrict__ bias,
                         const float* __restrict__ b4,
                         float* __restrict__ xout, float* __restrict__ x4out) {
    int t = threadIdx.x;
    int node = blockIdx.x * 8 + (t >> 5);
    int lane = t & 31;
    int start = row_off[node];           // multiple of 8 -> 32B aligned
    int cnt   = degi[node];
    int iters = (cnt + 7) >> 3;          // pairs of quads
    const int4*   ip = (const int4*)(csr_src + start);
    const float4* cp = (const float4*)(csr_cf + start);
    float acc0 = 0.f, acc1 = 0.f;
    if (iters > 0) {
        int4   iA = ip[0], iB = ip[1];
        float4 cA = cp[0], cB = cp[1];
        for (int k = 1; k < iters; k++) {
            int4   nA = ip[2 * k],     nB = ip[2 * k + 1];
            float4 dA = cp[2 * k],     dB = cp[2 * k + 1];
            acc0 += h[(size_t)iA.x * DIM + lane] * cA.x;
            acc1 += h[(size_t)iA.y * DIM + lane] * cA.y;
            acc0 += h[(size_t)iA.z * DIM + lane] * cA.z;
            acc1 += h[(size_t)iA.w * DIM + lane] * cA.w;
            acc0 += h[(size_t)iB.x * DIM + lane] * cB.x;
            acc1 += h[(size_t)iB.y * DIM + lane] * cB.y;
            acc0 += h[(size_t)iB.z * DIM + lane] * cB.z;
            acc1 += h[(size_t)iB.w * DIM + lane] * cB.w;
            iA = nA; iB = nB; cA = dA; cB = dB;
        }
        acc0 += h[(size_t)iA.x * DIM + lane] * cA.x;
        acc1 += h[(size_t)iA.y * DIM + lane] * cA.y;
        acc0 += h[(size_t)iA.z * DIM + lane] * cA.z;
        acc1 += h[(size_t)iA.w * DIM + lane] * cA.w;
        acc0 += h[(size_t)iB.x * DIM + lane] * cB.x;
        acc1 += h[(size_t)iB.y * DIM + lane] * cB.y;
        acc0 += h[(size_t)iB.z * DIM + lane] * cB.z;
        acc1 += h[(size_t)iB.w * DIM + lane] * cB.w;
    }
    float di = dinv[node];
    float outv = tanhf(acc0 + acc1 + h[(size_t)node * DIM + lane] * di + bias[lane]);
    xout[(size_t)node * DIM + lane] = outv;
    if (h4) {
        int cntp = iters << 3;
        float a4 = 0.f;
        for (int ee = lane; ee < cntp; ee += 32)
            a4 += h4[csr_src[start + ee]] * csr_cf[start + ee];
        for (int off = 16; off > 0; off >>= 1) a4 += __shfl_xor(a4, off, 32);
        if (lane == 0) x4out[node] = tanhf(a4 + h4[node] * di + b4[0]);
    }
}

// ---------------- sort pooling ----------------
__global__ void k_sortpool(const float* __restrict__ x4, int* __restrict__ sel) {
    __shared__ unsigned long long keys[512];
    int g = blockIdx.x, t = threadIdx.x;
    for (int i = t; i < 512; i += 256) {
        unsigned long long kk = 0xFFFFFFFFFFFFFFFFULL;
        if (i < NPER) {
            unsigned u = __float_as_uint(x4[g * NPER + i]);
            u = (u & 0x80000000u) ? ~u : (u | 0x80000000u);
            kk = ((unsigned long long)(~u) << 32) | (unsigned)i;
        }
        keys[i] = kk;
    }
    __syncthreads();
    for (int k = 2; k <= 512; k <<= 1)
        for (int j = k >> 1; j > 0; j >>= 1) {
            for (int i = t; i < 512; i += 256) {
                int l = i ^ j;
                if (l > i) {
                    unsigned long long a = keys[i], b = keys[l];
                    bool asc = ((i & k) == 0);
                    if ((a > b) == asc) { keys[i] = b; keys[l] = a; }
                }
            }
            __syncthreads();
        }
    for (int i = t; i < KTOP; i += 256)
        sel[g * KTOP + i] = g * NPER + (int)(unsigned)(keys[i] & 0xFFFFFFFFu);
}

// ---------------- conv1 (per-slot linear) + maxpool (1024 threads) ----------------
__global__ __launch_bounds__(1024) void
k_conv1pool(const float* __restrict__ x1, const float* __restrict__ x2,
            const float* __restrict__ x3, const float* __restrict__ x4,
            const int* __restrict__ sel, const float* __restrict__ cw1f,
            const float* __restrict__ cb1f, float* __restrict__ p1g) {
    __shared__ __align__(16) float xs[32 * 100];   // [q][k]
    __shared__ __align__(16) float ws[32 * 128];   // [q][c]
    __shared__ int nsh[KTOP];
    int g = blockIdx.x, t = threadIdx.x;
    if (t < KTOP) nsh[t] = sel[g * KTOP + t];
    int ct = (t & 31) * 4;              // channel tile
    int kt = (t >> 5) * 4;              // k tile (t<800 -> kt<100)
    bool act = (t < 800);
    float acc[4][4] = {};               // [k-off][c-off]
    for (int ch = 0; ch < 3; ch++) {
        const float* arr = (ch == 0) ? x1 : (ch == 1) ? x2 : x3;
        __syncthreads();
        for (int i = t; i < 3200; i += 1024) {      // q fastest → coalesced node rows
            int q = i & 31, k = i >> 5;
            xs[q * 100 + k] = arr[(size_t)nsh[k] * 32 + q];
        }
        for (int i = t; i < 4096; i += 1024) {      // c fastest → conflict-free LDS write
            int c = i & 127, q = i >> 7;
            ws[q * 128 + c] = cw1f[c * TOTALC + ch * 32 + q];
        }
        __syncthreads();
        if (act) {
            for (int q = 0; q < 32; q++) {
                float4 wv = *(const float4*)&ws[q * 128 + ct];
                float4 xv = *(const float4*)&xs[q * 100 + kt];
                float xa[4] = { xv.x, xv.y, xv.z, xv.w };
                float wa[4] = { wv.x, wv.y, wv.z, wv.w };
                #pragma unroll
                for (int a = 0; a < 4; a++)
                    #pragma unroll
                    for (int b = 0; b < 4; b++)
                        acc[a][b] += xa[a] * wa[b];
            }
        }
    }
    if (act) {
        float wa[4];
        #pragma unroll
        for (int b = 0; b < 4; b++) wa[b] = cw1f[(ct + b) * TOTALC + 96];
        #pragma unroll
        for (int a = 0; a < 4; a++) {   // tail channel q = 96 (x4)
            float xv = x4[nsh[kt + a]];
            #pragma unroll
            for (int b = 0; b < 4; b++) acc[a][b] += xv * wa[b];
        }
        int jbase = kt >> 1;
        #pragma unroll
        for (int b = 0; b < 4; b++) {
            float bias = cb1f[ct + b];
            float m0 = fmaxf(fmaxf(acc[0][b], acc[1][b]) + bias, 0.f);
            float m1 = fmaxf(fmaxf(acc[2][b], acc[3][b]) + bias, 0.f);
            p1g[((size_t)g * 128 + ct + b) * 50 + jbase]     = m0;
            p1g[((size_t)g * 128 + ct + b) * 50 + jbase + 1] = m1;
        }
    }
}

__global__ void k_w2t(const float* __restrict__ cw2f, float* __restrict__ w2t) {
    int i = blockIdx.x * 256 + threadIdx.x;
    if (i < 64 * 128 * 5) {
        int o = i / 640, r = i % 640, c = r / 5, q = r % 5;
        w2t[(c * 5 + q) * 64 + o] = cw2f[i];
    }
}

// ---------------- conv2 + fc1 + fc3 + log_softmax (1024 threads) ----------------
__global__ __launch_bounds__(1024) void
k_conv2fc(const float* __restrict__ p1g, const float* __restrict__ w2t,
          const float* __restrict__ cb2f,
          const float* __restrict__ fw1t, const float* __restrict__ fb1f,
          const float* __restrict__ fw3f, const float* __restrict__ fb3f,
          const int* __restrict__ flag, void* __restrict__ outp) {
    __shared__ __align__(16) float p1s[128 * 52];   // padded rows for aligned float4 windows
    __shared__ float flat[64 * 46];
    __shared__ float hpart[1024];
    __shared__ float hsh[128];
    int g = blockIdx.x, t = threadIdx.x;
    for (int i = t; i < 128 * 50; i += 1024) {
        int c = i / 50, p = i % 50;
        p1s[c * 52 + p] = p1g[(size_t)g * 6400 + i];
    }
    for (int i = t; i < 128 * 2; i += 1024) {       // zero pad cols 50,51
        int c = i >> 1;
        p1s[c * 52 + 50 + (i & 1)] = 0.f;
    }
    for (int i = t; i < 2944; i += 1024) flat[i] = 0.f;
    __syncthreads();
    {   // conv2: o = lane; (ph, c-eighth) over 16 segments; all 5 w-loads hoisted
        int o = t & 63;
        int seg = t >> 6;                // 0..15
        int ph = seg & 1, c8 = seg >> 1; // c8: 0..7
        int p0 = ph ? 24 : 0;
        int np = ph ? 22 : 24;
        float acc[24];
        #pragma unroll
        for (int p = 0; p < 24; p++) acc[p] = 0.f;
        int cbeg = c8 * 16;
        for (int c = cbeg; c < cbeg + 16; c++) {
            const float* wb = w2t + c * 320 + o;    // (c*5+q)*64+o
            float w0 = wb[0], w1 = wb[64], w2 = wb[128], w3 = wb[192], w4 = wb[256];
            float win[28];
            const float4* wsrc = (const float4*)&p1s[c * 52 + p0];
            #pragma unroll
            for (int v = 0; v < 7; v++) {
                float4 f = wsrc[v];
                win[4 * v] = f.x; win[4 * v + 1] = f.y; win[4 * v + 2] = f.z; win[4 * v + 3] = f.w;
            }
            #pragma unroll
            for (int p = 0; p < 24; p++)
                acc[p] += win[p] * w0 + win[p + 1] * w1 + win[p + 2] * w2
                        + win[p + 3] * w3 + win[p + 4] * w4;
        }
        for (int p = 0; p < np; p++) atomicAdd(&flat[o * 46 + p0 + p], acc[p]);
    }
    __syncthreads();
    for (int i = t; i < 2944; i += 1024) {
        int o = i / 46;
        flat[i] = fmaxf(flat[i] + cb2f[o], 0.f);
    }
    __syncthreads();
    {   // fc1: gg = t&127 output, slice = t>>7 covers 368 d's; fw1t coalesced over gg
        int gg = t & 127, slice = t >> 7;
        const float* fl = flat + slice * 368;
        const float* wp = fw1t + (size_t)slice * 368 * 128 + gg;
        float a = 0.f;
        #pragma unroll 8
        for (int d = 0; d < 368; d++) a += fl[d] * wp[(size_t)d * 128];
        hpart[t] = a;
    }
    __syncthreads();
    if (t < 128) {
        float s = fb1f[t];
        #pragma unroll
        for (int s2 = 0; s2 < 8; s2++) s += hpart[t + 128 * s2];
        hsh[t] = fmaxf(s, 0.f);
    }
    __syncthreads();
    if (t < 64) {   // fc3 + log_softmax: 64-lane parallel reduce
        float h0 = hsh[t], h1 = hsh[t + 64];
        float l0 = h0 * fw3f[t] + h1 * fw3f[t + 64];
        float l1 = h0 * fw3f[128 + t] + h1 * fw3f[192 + t];
        #pragma unroll
        for (int off = 32; off > 0; off >>= 1) {
            l0 += __shfl_down(l0, off, 64);
            l1 += __shfl_down(l1, off, 64);
        }
        if (t == 0) {
            l0 += fb3f[0]; l1 += fb3f[1];
            float m = fmaxf(l0, l1);
            float lse = m + logf(expf(l0 - m) + expf(l1 - m));
            if (flag[0]) {
                unsigned short* ob = (unsigned short*)outp;
                ob[g * 2 + 0] = f2bf(l0 - lse);
                ob[g * 2 + 1] = f2bf(l1 - lse);
            } else {
                float* of = (float*)outp;
                of[g * 2 + 0] = l0 - lse;
                of[g * 2 + 1] = l1 - lse;
            }
        }
    }
}

// ---------------- launch ----------------

extern "C" void kernel_launch(void* const* d_in, const int* in_sizes, int n_in,
                              void* d_out, int out_size, void* d_ws, size_t ws_size,
                              hipStream_t stream) {
    const void* x  = d_in[0];
    const int* ei  = (const int*)d_in[1];
    // d_in[2] = batch (arange/400, unused)

    char* p = (char*)d_ws;
    auto alloc = [&](size_t bytes) -> void* {
        void* r = (void*)p;
        p += (bytes + 255) & ~(size_t)255;
        return r;
    };
    int*      flag    = (int*)alloc(256);
    float*    wcv     = (float*)alloc((size_t)OW_TOT * 4);
    float*    fw1t    = (float*)alloc((size_t)376832 * 4);
    int*      ghist   = (int*)alloc((size_t)NBUCK * NCHUNK * 4);
    int*      bcnt    = (int*)alloc(1024 * 4);
    int*      boff    = (int*)alloc(1024 * 4);
    int*      bsums   = (int*)alloc(512 * 4);
    int*      degi    = (int*)alloc((size_t)NNODES * 4);
    int*      row_off = (int*)alloc((size_t)NNODES * 4);
    float*    dis     = (float*)alloc((size_t)NNODES * 4);
    float*    dinv    = (float*)alloc((size_t)NNODES * 4);
    unsigned* staged  = (unsigned*)alloc((size_t)NEDGES * 4);
    int*      csr_src = (int*)alloc((size_t)NPADE * 4);
    float*    csr_cf  = (float*)alloc((size_t)NPADE * 4);
    float*    hbuf    = (float*)alloc((size_t)NNODES * DIM * 4);
    float*    h4buf   = (float*)alloc((size_t)NNODES * 4);
    float*    x1      = (float*)alloc((size_t)NNODES * DIM * 4);
    float*    x2      = (float*)alloc((size_t)NNODES * DIM * 4);
    float*    x3      = (float*)alloc((size_t)NNODES * DIM * 4);
    float*    x4      = (float*)alloc((size_t)NNODES * 4);
    int*      sel     = (int*)alloc((size_t)NGRAPH * KTOP * 4);
    float*    p1g     = (float*)alloc((size_t)NGRAPH * 128 * 50 * 4);
    float*    w2t     = (float*)alloc((size_t)64 * 128 * 5 * 4);
    (void)in_sizes; (void)n_in; (void)out_size; (void)ws_size;

    k_detect<<<1, 256, 0, stream>>>((const unsigned int*)x, flag);
    Srcs sr;
    for (int i = 0; i < 16; i++) sr.p[i] = d_in[3 + i];
    k_convert<<<(OW_TOT + 255) / 256, 256, 0, stream>>>(sr, wcv, flag);
    k_w1t    <<<1472, 256, 0, stream>>>(wcv + OW_FW1, fw1t);

    k_hist     <<<NCHUNK, 1024, 0, stream>>>(ei, ghist);
    k_scanChunk<<<NBUCK, 256, 0, stream>>>(ghist, bcnt);
    k_scanB    <<<1, 1024, 0, stream>>>(bcnt, boff);
    k_binwrite <<<NCHUNK, 1024, 0, stream>>>(ei, boff, ghist, staged);
    k_nodecnt  <<<NBUCK, 256, 0, stream>>>(staged, boff, degi);
    k_nodeprep <<<391, 256, 0, stream>>>(degi, dis, dinv);
    k_bsum     <<<391, 256, 0, stream>>>(degi, bsums);
    k_scanb    <<<1, 512, 0, stream>>>(bsums, 391);
    k_scanf    <<<391, 256, 0, stream>>>(degi, bsums, row_off);
    k_csrfix   <<<NBUCK, 256, 0, stream>>>(staged, boff, row_off, dis, csr_src, csr_cf);

    k_mm1   <<<12500, 256, 0, stream>>>(x, wcv + OW_W1, flag, hbuf);
    k_gather<<<12500, 256, 0, stream>>>(hbuf, nullptr, csr_src, csr_cf, row_off, degi, dinv,
                                        wcv + OW_B1, nullptr, x1, nullptr);
    k_mm32  <<<12500, 256, 0, stream>>>(x1, wcv + OW_W2, nullptr, hbuf, nullptr);
    k_gather<<<12500, 256, 0, stream>>>(hbuf, nullptr, csr_src, csr_cf, row_off, degi, dinv,
                                        wcv + OW_B2, nullptr, x2, nullptr);
    k_mm32  <<<12500, 256, 0, stream>>>(x2, wcv + OW_W3, wcv + OW_W4, hbuf, h4buf);
    k_gather<<<12500, 256, 0, stream>>>(hbuf, h4buf, csr_src, csr_cf, row_off, degi, dinv,
                                        wcv + OW_B3, wcv + OW_B4, x3, x4);

    k_sortpool <<<NGRAPH, 256, 0, stream>>>(x4, sel);
    k_conv1pool<<<NGRAPH, 1024, 0, stream>>>(x1, x2, x3, x4, sel, wcv + OW_CW1, wcv + OW_CB1, p1g);
    k_w2t      <<<160, 256, 0, stream>>>(wcv + OW_CW2, w2t);
    k_conv2fc  <<<NGRAPH, 1024, 0, stream>>>(p1g, w2t, wcv + OW_CB2, fw1t, wcv + OW_FB1,
                                             wcv + OW_FW3, wcv + OW_FB3, flag, d_out);
}